// Round 1
// baseline (1635.790 us; speedup 1.0000x reference)
//
#include <hip/hip_runtime.h>
#include <cmath>

#define NN 100000

// ---------------- weight transpose (W[J][128] -> Wt[128][Jpad], zero-pad) ----------------
__global__ void transpose_w(const float* __restrict__ W, float* __restrict__ Wt,
                            int J, int Jpad) {
    int idx = blockIdx.x * 256 + threadIdx.x;
    int tot = 128 * Jpad;
    if (idx >= tot) return;
    int k = idx / Jpad, j = idx - k * Jpad;
    Wt[idx] = (j < J) ? W[j * 128 + k] : 0.f;
}

// ---------------- CSR build ----------------
__global__ void hist_k(const int* __restrict__ dst, int E, int* __restrict__ hist) {
    int stride = gridDim.x * blockDim.x;
    for (int i = blockIdx.x * blockDim.x + threadIdx.x; i < E; i += stride)
        atomicAdd(&hist[dst[i]], 1);
}

__global__ __launch_bounds__(256) void scan1_k(const int* __restrict__ hist, int n,
                                               int* __restrict__ rowptr,
                                               int* __restrict__ bsum) {
    __shared__ int sd[256];
    int t = threadIdx.x;
    int i = blockIdx.x * 256 + t;
    int v = (i < n) ? hist[i] : 0;
    sd[t] = v;
    __syncthreads();
    for (int off = 1; off < 256; off <<= 1) {
        int x = (t >= off) ? sd[t - off] : 0;
        __syncthreads();
        sd[t] += x;
        __syncthreads();
    }
    if (i < n) rowptr[i] = sd[t] - v;          // exclusive within block
    if (t == 255) bsum[blockIdx.x] = sd[255];
}

__global__ __launch_bounds__(512) void scan2_k(int* __restrict__ bsum, int nb) {
    __shared__ int sd[512];
    int t = threadIdx.x;
    int v = (t < nb) ? bsum[t] : 0;
    sd[t] = v;
    __syncthreads();
    for (int off = 1; off < 512; off <<= 1) {
        int x = (t >= off) ? sd[t - off] : 0;
        __syncthreads();
        sd[t] += x;
        __syncthreads();
    }
    if (t < nb) bsum[t] = sd[t] - v;           // exclusive
}

__global__ void scan3_k(int* __restrict__ rowptr, const int* __restrict__ bsum,
                        int* __restrict__ wr, int n, int total) {
    int i = blockIdx.x * 256 + threadIdx.x;
    if (i < n) {
        int v = rowptr[i] + bsum[i >> 8];
        rowptr[i] = v;
        wr[i] = v;
    }
    if (i == 0) rowptr[n] = total;
}

__global__ void fill_k(const int* __restrict__ src, const int* __restrict__ dst, int E,
                       int* __restrict__ wr, int* __restrict__ colv) {
    int stride = gridDim.x * blockDim.x;
    for (int i = blockIdx.x * blockDim.x + threadIdx.x; i < E; i += stride) {
        int d = dst[i];
        int slot = atomicAdd(&wr[d], 1);
        colv[slot] = src[i];
    }
}

// ---------------- projection + L2 normalize ----------------
// block = 256 threads = 8 row-groups x 32 col-groups; 32 rows/block, 4x4 per thread.
// X row-major [n][128]; Wt k-major [128][128]; Y = normalize(X@W.T + b)
__global__ __launch_bounds__(256) void lin_norm(const float* __restrict__ X,
                                                const float* __restrict__ Wt,
                                                const float* __restrict__ bias,
                                                float* __restrict__ Y) {
    __shared__ float xT[128 * 36];   // [k][row], pad 36
    const int t = threadIdx.x;
    const int base = blockIdx.x * 32;

    // stage 32x128 tile transposed into LDS (coalesced float4 reads)
#pragma unroll
    for (int i = 0; i < 4; i++) {
        int f = (i * 256 + t) * 4;              // flat float offset 0..4092
        int row = f >> 7, col = f & 127;
        const float4 v = *(const float4*)(X + (size_t)(base + row) * 128 + col);
        xT[(col + 0) * 36 + row] = v.x;
        xT[(col + 1) * 36 + row] = v.y;
        xT[(col + 2) * 36 + row] = v.z;
        xT[(col + 3) * 36 + row] = v.w;
    }
    __syncthreads();

    const int rg = t >> 5, cg = t & 31;
    float acc[4][4] = {};
#pragma unroll 4
    for (int k = 0; k < 128; k++) {
        const float4 a = *(const float4*)(&xT[k * 36 + rg * 4]);
        const float4 wv = *(const float4*)(Wt + k * 128 + cg * 4);
        const float av[4] = {a.x, a.y, a.z, a.w};
        const float wl[4] = {wv.x, wv.y, wv.z, wv.w};
#pragma unroll
        for (int r = 0; r < 4; r++)
#pragma unroll
            for (int c = 0; c < 4; c++) acc[r][c] = fmaf(av[r], wl[c], acc[r][c]);
    }

    const float4 bv = *(const float4*)(bias + cg * 4);
    const float bl[4] = {bv.x, bv.y, bv.z, bv.w};
#pragma unroll
    for (int r = 0; r < 4; r++) {
        float v0 = acc[r][0] + bl[0], v1 = acc[r][1] + bl[1];
        float v2 = acc[r][2] + bl[2], v3 = acc[r][3] + bl[3];
        float s = v0 * v0 + v1 * v1 + v2 * v2 + v3 * v3;
#pragma unroll
        for (int m = 16; m >= 1; m >>= 1) s += __shfl_xor(s, m, 64);
        const float sc = 1.f / fmaxf(sqrtf(s), 1e-12f);
        float4 o;
        o.x = v0 * sc; o.y = v1 * sc; o.z = v2 * sc; o.w = v3 * sc;
        *(float4*)(Y + (size_t)(base + rg * 4 + r) * 128 + cg * 4) = o;
    }
}

// ---------------- CSR mean-aggregate + ReLU ----------------
// one wave per node, float2 per lane covers the 128-f32 row
__global__ __launch_bounds__(256) void agg_k(const float* __restrict__ hp,
                                             const int* __restrict__ rowptr,
                                             const int* __restrict__ colv,
                                             float* __restrict__ outp) {
    const int lane = threadIdx.x & 63;
    const int wid = blockIdx.x * 4 + (threadIdx.x >> 6);
    const int nw = gridDim.x * 4;
    for (int node = wid; node < NN; node += nw) {
        const int s = rowptr[node], e = rowptr[node + 1];
        float ax = 0.f, ay = 0.f;
        const float* bp = hp + 2 * lane;
        for (int i = s; i < e; i++) {
            const int c = colv[i];
            const float2 v = *(const float2*)(bp + (size_t)c * 128);
            ax += v.x; ay += v.y;
        }
        const float inv = 1.f / fmaxf((float)(e - s), 1.f);
        float2 o;
        o.x = fmaxf(ax * inv, 0.f);
        o.y = fmaxf(ay * inv, 0.f);
        *(float2*)(outp + (size_t)node * 128 + 2 * lane) = o;
    }
}

// ---------------- post MLP (128->128, 128->40) + log_softmax ----------------
__global__ __launch_bounds__(256) void postmlp(const float* __restrict__ X,
                                               const float* __restrict__ Wp1t,
                                               const float* __restrict__ bp1,
                                               const float* __restrict__ Wp2t,  // [128][64] padded
                                               const float* __restrict__ bp2,
                                               float* __restrict__ Out) {
    __shared__ float xT[128 * 36];
    __shared__ float hT[128 * 36];
    const int t = threadIdx.x;
    const int base = blockIdx.x * 32;

#pragma unroll
    for (int i = 0; i < 4; i++) {
        int f = (i * 256 + t) * 4;
        int row = f >> 7, col = f & 127;
        const float4 v = *(const float4*)(X + (size_t)(base + row) * 128 + col);
        xT[(col + 0) * 36 + row] = v.x;
        xT[(col + 1) * 36 + row] = v.y;
        xT[(col + 2) * 36 + row] = v.z;
        xT[(col + 3) * 36 + row] = v.w;
    }
    __syncthreads();

    // stage 1: h1 = X @ Wp1.T + bp1  -> hT (transposed in LDS)
    {
        const int rg = t >> 5, cg = t & 31;
        float acc[4][4] = {};
#pragma unroll 4
        for (int k = 0; k < 128; k++) {
            const float4 a = *(const float4*)(&xT[k * 36 + rg * 4]);
            const float4 wv = *(const float4*)(Wp1t + k * 128 + cg * 4);
            const float av[4] = {a.x, a.y, a.z, a.w};
            const float wl[4] = {wv.x, wv.y, wv.z, wv.w};
#pragma unroll
            for (int r = 0; r < 4; r++)
#pragma unroll
                for (int c = 0; c < 4; c++) acc[r][c] = fmaf(av[r], wl[c], acc[r][c]);
        }
        const float4 bv = *(const float4*)(bp1 + cg * 4);
        const float bl[4] = {bv.x, bv.y, bv.z, bv.w};
#pragma unroll
        for (int r = 0; r < 4; r++)
#pragma unroll
            for (int c = 0; c < 4; c++)
                hT[(cg * 4 + c) * 36 + rg * 4 + r] = acc[r][c] + bl[c];
    }
    __syncthreads();

    // stage 2: logits = h1 @ Wp2.T + bp2 (cols padded to 64), then log_softmax
    {
        const int rg2 = t >> 4, cg2 = t & 15;     // 16 row-groups x 16 col-groups
        const bool valid = (cg2 < 10);            // cols 0..39 real
        float acc[2][4] = {};
#pragma unroll 4
        for (int k = 0; k < 128; k++) {
            const float2 a = *(const float2*)(&hT[k * 36 + rg2 * 2]);
            const float4 wv = *(const float4*)(Wp2t + k * 64 + cg2 * 4);
            const float wl[4] = {wv.x, wv.y, wv.z, wv.w};
#pragma unroll
            for (int c = 0; c < 4; c++) {
                acc[0][c] = fmaf(a.x, wl[c], acc[0][c]);
                acc[1][c] = fmaf(a.y, wl[c], acc[1][c]);
            }
        }
        float bl[4] = {0.f, 0.f, 0.f, 0.f};
        if (valid) {
#pragma unroll
            for (int c = 0; c < 4; c++) bl[c] = bp2[cg2 * 4 + c];
        }
#pragma unroll
        for (int r = 0; r < 2; r++) {
            float v[4];
#pragma unroll
            for (int c = 0; c < 4; c++) v[c] = acc[r][c] + bl[c];
            float m = valid ? fmaxf(fmaxf(v[0], v[1]), fmaxf(v[2], v[3])) : -1e30f;
#pragma unroll
            for (int msk = 8; msk >= 1; msk >>= 1) m = fmaxf(m, __shfl_xor(m, msk, 64));
            float se = 0.f;
            if (valid) {
#pragma unroll
                for (int c = 0; c < 4; c++) se += expf(v[c] - m);
            }
#pragma unroll
            for (int msk = 8; msk >= 1; msk >>= 1) se += __shfl_xor(se, msk, 64);
            const float lse = logf(se);
            if (valid) {
                float4 o;
                o.x = v[0] - m - lse; o.y = v[1] - m - lse;
                o.z = v[2] - m - lse; o.w = v[3] - m - lse;
                const int row = base + rg2 * 2 + r;
                *(float4*)(Out + (size_t)row * 40 + cg2 * 4) = o;
            }
        }
    }
}

extern "C" void kernel_launch(void* const* d_in, const int* in_sizes, int n_in,
                              void* d_out, int out_size, void* d_ws, size_t ws_size,
                              hipStream_t stream) {
    const float* x   = (const float*)d_in[0];
    const int*   ei  = (const int*)d_in[1];
    const float* W0  = (const float*)d_in[2];
    const float* b0  = (const float*)d_in[3];
    const float* W1  = (const float*)d_in[4];
    const float* b1  = (const float*)d_in[5];
    const float* W2  = (const float*)d_in[6];
    const float* b2  = (const float*)d_in[7];
    const float* Wp1 = (const float*)d_in[8];
    const float* bp1 = (const float*)d_in[9];
    const float* Wp2 = (const float*)d_in[10];
    const float* bp2 = (const float*)d_in[11];
    float* out = (float*)d_out;

    const int E = in_sizes[1] / 2;
    const int* srcv = ei;
    const int* dstv = ei + E;

    char* w = (char*)d_ws;
    auto alloc = [&](size_t sz) {
        char* p = w;
        w += (sz + 255) & ~(size_t)255;
        return p;
    };
    float* B0     = (float*)alloc(sizeof(float) * (size_t)NN * 128);
    float* B1     = (float*)alloc(sizeof(float) * (size_t)NN * 128);
    int*   colv   = (int*)alloc(sizeof(int) * (size_t)E);
    int*   hist   = (int*)alloc(sizeof(int) * NN);
    int*   rowptr = (int*)alloc(sizeof(int) * (NN + 1));
    int*   wrc    = (int*)alloc(sizeof(int) * NN);
    int*   bsum   = (int*)alloc(sizeof(int) * 512);
    float* Wt0    = (float*)alloc(sizeof(float) * 128 * 128);
    float* Wt1    = (float*)alloc(sizeof(float) * 128 * 128);
    float* Wt2    = (float*)alloc(sizeof(float) * 128 * 128);
    float* Wtp1   = (float*)alloc(sizeof(float) * 128 * 128);
    float* Wtp2   = (float*)alloc(sizeof(float) * 128 * 64);

    // weight transposes (tiny)
    transpose_w<<<64, 256, 0, stream>>>(W0, Wt0, 128, 128);
    transpose_w<<<64, 256, 0, stream>>>(W1, Wt1, 128, 128);
    transpose_w<<<64, 256, 0, stream>>>(W2, Wt2, 128, 128);
    transpose_w<<<64, 256, 0, stream>>>(Wp1, Wtp1, 128, 128);
    transpose_w<<<32, 256, 0, stream>>>(Wp2, Wtp2, 40, 64);

    // CSR build
    hipMemsetAsync(hist, 0, sizeof(int) * NN, stream);
    hist_k<<<2048, 256, 0, stream>>>(dstv, E, hist);
    const int nb = (NN + 255) / 256;  // 391
    scan1_k<<<nb, 256, 0, stream>>>(hist, NN, rowptr, bsum);
    scan2_k<<<1, 512, 0, stream>>>(bsum, nb);
    scan3_k<<<nb, 256, 0, stream>>>(rowptr, bsum, wrc, NN, E);
    fill_k<<<2048, 256, 0, stream>>>(srcv, dstv, E, wrc, colv);

    // 3 SAGE layers
    lin_norm<<<NN / 32, 256, 0, stream>>>(x, Wt0, b0, B0);
    agg_k<<<4096, 256, 0, stream>>>(B0, rowptr, colv, B1);
    lin_norm<<<NN / 32, 256, 0, stream>>>(B1, Wt1, b1, B0);
    agg_k<<<4096, 256, 0, stream>>>(B0, rowptr, colv, B1);
    lin_norm<<<NN / 32, 256, 0, stream>>>(B1, Wt2, b2, B0);
    agg_k<<<4096, 256, 0, stream>>>(B0, rowptr, colv, B1);

    // post-MLP + log_softmax
    postmlp<<<NN / 32, 256, 0, stream>>>(B1, Wtp1, bp1, Wtp2, bp2, out);
}

// Round 2
// 1079.286 us; speedup vs baseline: 1.5156x; 1.5156x over previous
//
#include <hip/hip_runtime.h>
#include <cmath>

#define NN 100000

typedef unsigned int uint32;
typedef unsigned short ushort16;

__device__ __forceinline__ float bf2f(ushort16 u) {
    return __uint_as_float(((uint32)u) << 16);
}
__device__ __forceinline__ ushort16 f2bf(float f) {
    uint32 b = __float_as_uint(f);
    uint32 r = (b + 0x7FFFu + ((b >> 16) & 1u)) >> 16;   // RNE
    return (ushort16)r;
}

// ---------------- weight transpose (W[J][128] -> Wt[128][Jpad], zero-pad) ----------------
__global__ void transpose_w(const float* __restrict__ W, float* __restrict__ Wt,
                            int J, int Jpad) {
    int idx = blockIdx.x * 256 + threadIdx.x;
    int tot = 128 * Jpad;
    if (idx >= tot) return;
    int k = idx / Jpad, j = idx - k * Jpad;
    Wt[idx] = (j < J) ? W[j * 128 + k] : 0.f;
}

// ---------------- CSR build ----------------
__global__ void hist_k(const int* __restrict__ dst, int E, int* __restrict__ hist) {
    int stride = gridDim.x * blockDim.x;
    for (int i = blockIdx.x * blockDim.x + threadIdx.x; i < E; i += stride)
        atomicAdd(&hist[dst[i]], 1);
}

__global__ __launch_bounds__(256) void scan1_k(const int* __restrict__ hist, int n,
                                               int* __restrict__ rowptr,
                                               int* __restrict__ bsum) {
    __shared__ int sd[256];
    int t = threadIdx.x;
    int i = blockIdx.x * 256 + t;
    int v = (i < n) ? hist[i] : 0;
    sd[t] = v;
    __syncthreads();
    for (int off = 1; off < 256; off <<= 1) {
        int x = (t >= off) ? sd[t - off] : 0;
        __syncthreads();
        sd[t] += x;
        __syncthreads();
    }
    if (i < n) rowptr[i] = sd[t] - v;          // exclusive within block
    if (t == 255) bsum[blockIdx.x] = sd[255];
}

__global__ __launch_bounds__(512) void scan2_k(int* __restrict__ bsum, int nb) {
    __shared__ int sd[512];
    int t = threadIdx.x;
    int v = (t < nb) ? bsum[t] : 0;
    sd[t] = v;
    __syncthreads();
    for (int off = 1; off < 512; off <<= 1) {
        int x = (t >= off) ? sd[t - off] : 0;
        __syncthreads();
        sd[t] += x;
        __syncthreads();
    }
    if (t < nb) bsum[t] = sd[t] - v;           // exclusive
}

__global__ void scan3_k(int* __restrict__ rowptr, const int* __restrict__ bsum,
                        int* __restrict__ wr, int n, int total) {
    int i = blockIdx.x * 256 + threadIdx.x;
    if (i < n) {
        int v = rowptr[i] + bsum[i >> 8];
        rowptr[i] = v;
        wr[i] = v;
    }
    if (i == 0) rowptr[n] = total;
}

__global__ void fill_k(const int* __restrict__ src, const int* __restrict__ dst, int E,
                       int* __restrict__ wr, int* __restrict__ colv) {
    int stride = gridDim.x * blockDim.x;
    for (int i = blockIdx.x * blockDim.x + threadIdx.x; i < E; i += stride) {
        int d = dst[i];
        int slot = atomicAdd(&wr[d], 1);
        colv[slot] = src[i];
    }
}

// ---------------- projection + L2 normalize (bf16 output for the gather) ----------------
// block = 256 threads = 8 row-groups x 32 col-groups; 32 rows/block, 4x4 per thread.
__global__ __launch_bounds__(256) void lin_norm(const float* __restrict__ X,
                                                const float* __restrict__ Wt,
                                                const float* __restrict__ bias,
                                                ushort16* __restrict__ Y) {
    __shared__ float xT[128 * 36];   // [k][row], pad 36
    const int t = threadIdx.x;
    const int base = blockIdx.x * 32;

#pragma unroll
    for (int i = 0; i < 4; i++) {
        int f = (i * 256 + t) * 4;
        int row = f >> 7, col = f & 127;
        const float4 v = *(const float4*)(X + (size_t)(base + row) * 128 + col);
        xT[(col + 0) * 36 + row] = v.x;
        xT[(col + 1) * 36 + row] = v.y;
        xT[(col + 2) * 36 + row] = v.z;
        xT[(col + 3) * 36 + row] = v.w;
    }
    __syncthreads();

    const int rg = t >> 5, cg = t & 31;
    float acc[4][4] = {};
#pragma unroll 4
    for (int k = 0; k < 128; k++) {
        const float4 a = *(const float4*)(&xT[k * 36 + rg * 4]);
        const float4 wv = *(const float4*)(Wt + k * 128 + cg * 4);
        const float av[4] = {a.x, a.y, a.z, a.w};
        const float wl[4] = {wv.x, wv.y, wv.z, wv.w};
#pragma unroll
        for (int r = 0; r < 4; r++)
#pragma unroll
            for (int c = 0; c < 4; c++) acc[r][c] = fmaf(av[r], wl[c], acc[r][c]);
    }

    const float4 bv = *(const float4*)(bias + cg * 4);
    const float bl[4] = {bv.x, bv.y, bv.z, bv.w};
#pragma unroll
    for (int r = 0; r < 4; r++) {
        float v0 = acc[r][0] + bl[0], v1 = acc[r][1] + bl[1];
        float v2 = acc[r][2] + bl[2], v3 = acc[r][3] + bl[3];
        float s = v0 * v0 + v1 * v1 + v2 * v2 + v3 * v3;
#pragma unroll
        for (int m = 16; m >= 1; m >>= 1) s += __shfl_xor(s, m, 64);
        const float sc = 1.f / fmaxf(sqrtf(s), 1e-12f);
        ushort16 o[4];
        o[0] = f2bf(v0 * sc); o[1] = f2bf(v1 * sc);
        o[2] = f2bf(v2 * sc); o[3] = f2bf(v3 * sc);
        *(uint2*)(Y + (size_t)(base + rg * 4 + r) * 128 + cg * 4) = *(uint2*)o;
    }
}

// ---------------- CSR mean-aggregate + ReLU (bf16 gather) ----------------
// wave = 2 half-waves; each half-wave (32 lanes) covers one edge row:
// lane l32 loads 4 bf16 (8B) at col l32*4. half 0 takes even list slots, half 1 odd.
__global__ __launch_bounds__(256) void agg_k(const ushort16* __restrict__ hp,
                                             const int* __restrict__ rowptr,
                                             const int* __restrict__ colv,
                                             float* __restrict__ outp) {
    const int lane = threadIdx.x & 63;
    const int half = lane >> 5;
    const int l32 = lane & 31;
    const int wid = blockIdx.x * 4 + (threadIdx.x >> 6);
    const int nw = gridDim.x * 4;

    for (int node = wid; node < NN; node += nw) {
        const int s = rowptr[node], e = rowptr[node + 1];
        float a0 = 0.f, a1 = 0.f, a2 = 0.f, a3 = 0.f;
        const size_t coff = (size_t)l32 * 4;

        int i = s + half;
        // unroll x2: two edges in flight per half-wave
        for (; i + 2 < e; i += 4) {
            const int c1 = colv[i];
            const int c2 = colv[i + 2];
            const uint2 u1 = *(const uint2*)(hp + (size_t)c1 * 128 + coff);
            const uint2 u2 = *(const uint2*)(hp + (size_t)c2 * 128 + coff);
            a0 += bf2f((ushort16)(u1.x & 0xffff)) + bf2f((ushort16)(u2.x & 0xffff));
            a1 += bf2f((ushort16)(u1.x >> 16))    + bf2f((ushort16)(u2.x >> 16));
            a2 += bf2f((ushort16)(u1.y & 0xffff)) + bf2f((ushort16)(u2.y & 0xffff));
            a3 += bf2f((ushort16)(u1.y >> 16))    + bf2f((ushort16)(u2.y >> 16));
        }
        if (i < e) {
            const int c1 = colv[i];
            const uint2 u1 = *(const uint2*)(hp + (size_t)c1 * 128 + coff);
            a0 += bf2f((ushort16)(u1.x & 0xffff));
            a1 += bf2f((ushort16)(u1.x >> 16));
            a2 += bf2f((ushort16)(u1.y & 0xffff));
            a3 += bf2f((ushort16)(u1.y >> 16));
        }

        // combine the two half-wave partial sums
        a0 += __shfl_xor(a0, 32, 64);
        a1 += __shfl_xor(a1, 32, 64);
        a2 += __shfl_xor(a2, 32, 64);
        a3 += __shfl_xor(a3, 32, 64);

        if (half == 0) {
            const float inv = 1.f / fmaxf((float)(e - s), 1.f);
            float4 o;
            o.x = fmaxf(a0 * inv, 0.f);
            o.y = fmaxf(a1 * inv, 0.f);
            o.z = fmaxf(a2 * inv, 0.f);
            o.w = fmaxf(a3 * inv, 0.f);
            *(float4*)(outp + (size_t)node * 128 + l32 * 4) = o;
        }
    }
}

// ---------------- post MLP (128->128, 128->40) + log_softmax ----------------
__global__ __launch_bounds__(256) void postmlp(const float* __restrict__ X,
                                               const float* __restrict__ Wp1t,
                                               const float* __restrict__ bp1,
                                               const float* __restrict__ Wp2t,  // [128][64] padded
                                               const float* __restrict__ bp2,
                                               float* __restrict__ Out) {
    __shared__ float xT[128 * 36];
    __shared__ float hT[128 * 36];
    const int t = threadIdx.x;
    const int base = blockIdx.x * 32;

#pragma unroll
    for (int i = 0; i < 4; i++) {
        int f = (i * 256 + t) * 4;
        int row = f >> 7, col = f & 127;
        const float4 v = *(const float4*)(X + (size_t)(base + row) * 128 + col);
        xT[(col + 0) * 36 + row] = v.x;
        xT[(col + 1) * 36 + row] = v.y;
        xT[(col + 2) * 36 + row] = v.z;
        xT[(col + 3) * 36 + row] = v.w;
    }
    __syncthreads();

    {
        const int rg = t >> 5, cg = t & 31;
        float acc[4][4] = {};
#pragma unroll 4
        for (int k = 0; k < 128; k++) {
            const float4 a = *(const float4*)(&xT[k * 36 + rg * 4]);
            const float4 wv = *(const float4*)(Wp1t + k * 128 + cg * 4);
            const float av[4] = {a.x, a.y, a.z, a.w};
            const float wl[4] = {wv.x, wv.y, wv.z, wv.w};
#pragma unroll
            for (int r = 0; r < 4; r++)
#pragma unroll
                for (int c = 0; c < 4; c++) acc[r][c] = fmaf(av[r], wl[c], acc[r][c]);
        }
        const float4 bv = *(const float4*)(bp1 + cg * 4);
        const float bl[4] = {bv.x, bv.y, bv.z, bv.w};
#pragma unroll
        for (int r = 0; r < 4; r++)
#pragma unroll
            for (int c = 0; c < 4; c++)
                hT[(cg * 4 + c) * 36 + rg * 4 + r] = acc[r][c] + bl[c];
    }
    __syncthreads();

    {
        const int rg2 = t >> 4, cg2 = t & 15;     // 16 row-groups x 16 col-groups
        const bool valid = (cg2 < 10);
        float acc[2][4] = {};
#pragma unroll 4
        for (int k = 0; k < 128; k++) {
            const float2 a = *(const float2*)(&hT[k * 36 + rg2 * 2]);
            const float4 wv = *(const float4*)(Wp2t + k * 64 + cg2 * 4);
            const float wl[4] = {wv.x, wv.y, wv.z, wv.w};
#pragma unroll
            for (int c = 0; c < 4; c++) {
                acc[0][c] = fmaf(a.x, wl[c], acc[0][c]);
                acc[1][c] = fmaf(a.y, wl[c], acc[1][c]);
            }
        }
        float bl[4] = {0.f, 0.f, 0.f, 0.f};
        if (valid) {
#pragma unroll
            for (int c = 0; c < 4; c++) bl[c] = bp2[cg2 * 4 + c];
        }
#pragma unroll
        for (int r = 0; r < 2; r++) {
            float v[4];
#pragma unroll
            for (int c = 0; c < 4; c++) v[c] = acc[r][c] + bl[c];
            float m = valid ? fmaxf(fmaxf(v[0], v[1]), fmaxf(v[2], v[3])) : -1e30f;
#pragma unroll
            for (int msk = 8; msk >= 1; msk >>= 1) m = fmaxf(m, __shfl_xor(m, msk, 64));
            float se = 0.f;
            if (valid) {
#pragma unroll
                for (int c = 0; c < 4; c++) se += expf(v[c] - m);
            }
#pragma unroll
            for (int msk = 8; msk >= 1; msk >>= 1) se += __shfl_xor(se, msk, 64);
            const float lse = logf(se);
            if (valid) {
                float4 o;
                o.x = v[0] - m - lse; o.y = v[1] - m - lse;
                o.z = v[2] - m - lse; o.w = v[3] - m - lse;
                const int row = base + rg2 * 2 + r;
                *(float4*)(Out + (size_t)row * 40 + cg2 * 4) = o;
            }
        }
    }
}

extern "C" void kernel_launch(void* const* d_in, const int* in_sizes, int n_in,
                              void* d_out, int out_size, void* d_ws, size_t ws_size,
                              hipStream_t stream) {
    const float* x   = (const float*)d_in[0];
    const int*   ei  = (const int*)d_in[1];
    const float* W0  = (const float*)d_in[2];
    const float* b0  = (const float*)d_in[3];
    const float* W1  = (const float*)d_in[4];
    const float* b1  = (const float*)d_in[5];
    const float* W2  = (const float*)d_in[6];
    const float* b2  = (const float*)d_in[7];
    const float* Wp1 = (const float*)d_in[8];
    const float* bp1 = (const float*)d_in[9];
    const float* Wp2 = (const float*)d_in[10];
    const float* bp2 = (const float*)d_in[11];
    float* out = (float*)d_out;

    const int E = in_sizes[1] / 2;
    const int* srcv = ei;
    const int* dstv = ei + E;

    char* w = (char*)d_ws;
    auto alloc = [&](size_t sz) {
        char* p = w;
        w += (sz + 255) & ~(size_t)255;
        return p;
    };
    ushort16* H  = (ushort16*)alloc(sizeof(ushort16) * (size_t)NN * 128);  // bf16 h table
    float* B1    = (float*)alloc(sizeof(float) * (size_t)NN * 128);        // f32 agg out
    int*   colv   = (int*)alloc(sizeof(int) * (size_t)E);
    int*   hist   = (int*)alloc(sizeof(int) * NN);
    int*   rowptr = (int*)alloc(sizeof(int) * (NN + 1));
    int*   wrc    = (int*)alloc(sizeof(int) * NN);
    int*   bsum   = (int*)alloc(sizeof(int) * 512);
    float* Wt0    = (float*)alloc(sizeof(float) * 128 * 128);
    float* Wt1    = (float*)alloc(sizeof(float) * 128 * 128);
    float* Wt2    = (float*)alloc(sizeof(float) * 128 * 128);
    float* Wtp1   = (float*)alloc(sizeof(float) * 128 * 128);
    float* Wtp2   = (float*)alloc(sizeof(float) * 128 * 64);

    transpose_w<<<64, 256, 0, stream>>>(W0, Wt0, 128, 128);
    transpose_w<<<64, 256, 0, stream>>>(W1, Wt1, 128, 128);
    transpose_w<<<64, 256, 0, stream>>>(W2, Wt2, 128, 128);
    transpose_w<<<64, 256, 0, stream>>>(Wp1, Wtp1, 128, 128);
    transpose_w<<<32, 256, 0, stream>>>(Wp2, Wtp2, 40, 64);

    // CSR build
    hipMemsetAsync(hist, 0, sizeof(int) * NN, stream);
    hist_k<<<2048, 256, 0, stream>>>(dstv, E, hist);
    const int nb = (NN + 255) / 256;  // 391
    scan1_k<<<nb, 256, 0, stream>>>(hist, NN, rowptr, bsum);
    scan2_k<<<1, 512, 0, stream>>>(bsum, nb);
    scan3_k<<<nb, 256, 0, stream>>>(rowptr, bsum, wrc, NN, E);
    fill_k<<<2048, 256, 0, stream>>>(srcv, dstv, E, wrc, colv);

    // 3 SAGE layers
    lin_norm<<<NN / 32, 256, 0, stream>>>(x, Wt0, b0, H);
    agg_k<<<4096, 256, 0, stream>>>(H, rowptr, colv, B1);
    lin_norm<<<NN / 32, 256, 0, stream>>>(B1, Wt1, b1, H);
    agg_k<<<4096, 256, 0, stream>>>(H, rowptr, colv, B1);
    lin_norm<<<NN / 32, 256, 0, stream>>>(B1, Wt2, b2, H);
    agg_k<<<4096, 256, 0, stream>>>(H, rowptr, colv, B1);

    // post-MLP + log_softmax
    postmlp<<<NN / 32, 256, 0, stream>>>(B1, Wtp1, bp1, Wtp2, bp2, out);
}

// Round 3
// 698.568 us; speedup vs baseline: 2.3416x; 1.5450x over previous
//
#include <hip/hip_runtime.h>
#include <cmath>

#define NN 100000
#define NB 512          // dst buckets
#define NLOC 196        // nodes per bucket (512*196 = 100352 >= NN)
#define CAP 7168        // per-bucket edge capacity (mean 6272, sigma 79 -> +11 sigma)
#define CHUNK 8192      // edges per csr_k1 block

typedef unsigned int uint32;
typedef unsigned short ushort16;

__device__ __forceinline__ float bf2f(ushort16 u) {
    return __uint_as_float(((uint32)u) << 16);
}
__device__ __forceinline__ ushort16 f2bf(float f) {
    uint32 b = __float_as_uint(f);
    uint32 r = (b + 0x7FFFu + ((b >> 16) & 1u)) >> 16;   // RNE
    return (ushort16)r;
}

// ---------------- weight transpose (W[J][128] -> Wt[128][Jpad], zero-pad) ----------------
__global__ void transpose_w(const float* __restrict__ W, float* __restrict__ Wt,
                            int J, int Jpad) {
    int idx = blockIdx.x * 256 + threadIdx.x;
    int tot = 128 * Jpad;
    if (idx >= tot) return;
    int k = idx / Jpad, j = idx - k * Jpad;
    Wt[idx] = (j < J) ? W[j * 128 + k] : 0.f;
}

// ---------------- CSR build: pass 1 — bucket partition ----------------
// edges -> per-bucket regions of ebuf, packed src | (dst_local << 17)
__global__ __launch_bounds__(256) void csr_k1(const int* __restrict__ srcv,
                                              const int* __restrict__ dstv, int E,
                                              int* __restrict__ cursor,
                                              uint32* __restrict__ ebuf) {
    __shared__ int lhist[NB];
    __shared__ int lbase[NB];
    __shared__ int lcnt[NB];
    const int t = threadIdx.x;
    const int e0 = blockIdx.x * CHUNK;
    const int e1 = min(e0 + CHUNK, E);

    for (int i = t; i < NB; i += 256) { lhist[i] = 0; lcnt[i] = 0; }
    __syncthreads();
    for (int i = e0 + t; i < e1; i += 256)
        atomicAdd(&lhist[dstv[i] / NLOC], 1);
    __syncthreads();
    for (int i = t; i < NB; i += 256)
        lbase[i] = lhist[i] ? atomicAdd(&cursor[i], lhist[i]) : 0;
    __syncthreads();
    for (int i = e0 + t; i < e1; i += 256) {
        const int d = dstv[i];
        const int s = srcv[i];
        const int b = d / NLOC;
        const int pos = lbase[b] + atomicAdd(&lcnt[b], 1);
        if (pos < CAP)
            ebuf[(size_t)b * CAP + pos] = (uint32)s | ((uint32)(d - b * NLOC) << 17);
    }
}

// ---------------- CSR build: bucket-start scan (512 values, 1 block) ----------------
__global__ __launch_bounds__(512) void scanb_k(const int* __restrict__ cursor,
                                               int* __restrict__ bstart) {
    __shared__ int sd[512];
    const int t = threadIdx.x;
    const int v = cursor[t];
    sd[t] = v;
    __syncthreads();
    for (int off = 1; off < 512; off <<= 1) {
        int x = (t >= off) ? sd[t - off] : 0;
        __syncthreads();
        sd[t] += x;
        __syncthreads();
    }
    bstart[t] = sd[t] - v;   // exclusive
}

// ---------------- CSR build: pass 2 — per-bucket rowptr + colv scatter ----------------
__global__ __launch_bounds__(256) void csr_k2(const uint32* __restrict__ ebuf,
                                              const int* __restrict__ cursor,
                                              const int* __restrict__ bstart,
                                              int* __restrict__ rowptr,
                                              int* __restrict__ colv, int Etot) {
    __shared__ int sd[256];
    __shared__ int loc[256];
    __shared__ int cnt[256];
    const int b = blockIdx.x;
    const int t = threadIdx.x;
    const int n = cursor[b];
    const int n0 = b * NLOC;
    const int nloc = min(NN - n0, NLOC);
    const int bst = bstart[b];
    const uint32* seg = ebuf + (size_t)b * CAP;

    sd[t] = 0; cnt[t] = 0;
    __syncthreads();
    for (int i = t; i < n; i += 256)
        atomicAdd(&sd[seg[i] >> 17], 1);
    __syncthreads();
    const int v = sd[t];
    __syncthreads();
    for (int off = 1; off < 256; off <<= 1) {
        int x = (t >= off) ? sd[t - off] : 0;
        __syncthreads();
        sd[t] += x;
        __syncthreads();
    }
    loc[t] = sd[t] - v;   // exclusive degree prefix within bucket
    __syncthreads();
    if (t < nloc) rowptr[n0 + t] = bst + loc[t];
    if (b == 0 && t == 0) rowptr[NN] = Etot;
    for (int i = t; i < n; i += 256) {
        const uint32 p = seg[i];
        const int l = p >> 17;
        const int src = p & 0x1FFFF;
        const int pos = atomicAdd(&cnt[l], 1);
        colv[bst + loc[l] + pos] = src;
    }
}

// ---------------- projection + L2 normalize (bf16 output for the gather) ----------------
__global__ __launch_bounds__(256) void lin_norm(const float* __restrict__ X,
                                                const float* __restrict__ Wt,
                                                const float* __restrict__ bias,
                                                ushort16* __restrict__ Y) {
    __shared__ float xT[128 * 36];   // [k][row], pad 36
    const int t = threadIdx.x;
    const int base = blockIdx.x * 32;

#pragma unroll
    for (int i = 0; i < 4; i++) {
        int f = (i * 256 + t) * 4;
        int row = f >> 7, col = f & 127;
        const float4 v = *(const float4*)(X + (size_t)(base + row) * 128 + col);
        xT[(col + 0) * 36 + row] = v.x;
        xT[(col + 1) * 36 + row] = v.y;
        xT[(col + 2) * 36 + row] = v.z;
        xT[(col + 3) * 36 + row] = v.w;
    }
    __syncthreads();

    const int rg = t >> 5, cg = t & 31;
    float acc[4][4] = {};
#pragma unroll 4
    for (int k = 0; k < 128; k++) {
        const float4 a = *(const float4*)(&xT[k * 36 + rg * 4]);
        const float4 wv = *(const float4*)(Wt + k * 128 + cg * 4);
        const float av[4] = {a.x, a.y, a.z, a.w};
        const float wl[4] = {wv.x, wv.y, wv.z, wv.w};
#pragma unroll
        for (int r = 0; r < 4; r++)
#pragma unroll
            for (int c = 0; c < 4; c++) acc[r][c] = fmaf(av[r], wl[c], acc[r][c]);
    }

    const float4 bv = *(const float4*)(bias + cg * 4);
    const float bl[4] = {bv.x, bv.y, bv.z, bv.w};
#pragma unroll
    for (int r = 0; r < 4; r++) {
        float v0 = acc[r][0] + bl[0], v1 = acc[r][1] + bl[1];
        float v2 = acc[r][2] + bl[2], v3 = acc[r][3] + bl[3];
        float s = v0 * v0 + v1 * v1 + v2 * v2 + v3 * v3;
#pragma unroll
        for (int m = 16; m >= 1; m >>= 1) s += __shfl_xor(s, m, 64);
        const float sc = 1.f / fmaxf(sqrtf(s), 1e-12f);
        ushort16 o[4];
        o[0] = f2bf(v0 * sc); o[1] = f2bf(v1 * sc);
        o[2] = f2bf(v2 * sc); o[3] = f2bf(v3 * sc);
        *(uint2*)(Y + (size_t)(base + rg * 4 + r) * 128 + cg * 4) = *(uint2*)o;
    }
}

// ---------------- CSR mean-aggregate + ReLU (bf16 gather) ----------------
// wave = 4 quarter-waves; each quarter (16 lanes x 16B) covers one edge row;
// 2-deep unroll -> 8 edge rows in flight per wave.
__global__ __launch_bounds__(256) void agg_k(const ushort16* __restrict__ hp,
                                             const int* __restrict__ rowptr,
                                             const int* __restrict__ colv,
                                             float* __restrict__ outp) {
    const int lane = threadIdx.x & 63;
    const int q = lane >> 4;
    const int l16 = lane & 15;
    const int wid = blockIdx.x * 4 + (threadIdx.x >> 6);
    const int nw = gridDim.x * 4;

    for (int node = wid; node < NN; node += nw) {
        const int s = rowptr[node], e = rowptr[node + 1];
        float a[8] = {};
        const ushort16* bp = hp + (size_t)l16 * 8;

        int i = s + q;
        for (; i + 4 < e; i += 8) {
            const int c1 = colv[i];
            const int c2 = colv[i + 4];
            const uint4 u1 = *(const uint4*)(bp + (size_t)c1 * 128);
            const uint4 u2 = *(const uint4*)(bp + (size_t)c2 * 128);
            a[0] += __uint_as_float(u1.x << 16) + __uint_as_float(u2.x << 16);
            a[1] += __uint_as_float(u1.x & 0xffff0000u) + __uint_as_float(u2.x & 0xffff0000u);
            a[2] += __uint_as_float(u1.y << 16) + __uint_as_float(u2.y << 16);
            a[3] += __uint_as_float(u1.y & 0xffff0000u) + __uint_as_float(u2.y & 0xffff0000u);
            a[4] += __uint_as_float(u1.z << 16) + __uint_as_float(u2.z << 16);
            a[5] += __uint_as_float(u1.z & 0xffff0000u) + __uint_as_float(u2.z & 0xffff0000u);
            a[6] += __uint_as_float(u1.w << 16) + __uint_as_float(u2.w << 16);
            a[7] += __uint_as_float(u1.w & 0xffff0000u) + __uint_as_float(u2.w & 0xffff0000u);
        }
        if (i < e) {
            const int c1 = colv[i];
            const uint4 u1 = *(const uint4*)(bp + (size_t)c1 * 128);
            a[0] += __uint_as_float(u1.x << 16);
            a[1] += __uint_as_float(u1.x & 0xffff0000u);
            a[2] += __uint_as_float(u1.y << 16);
            a[3] += __uint_as_float(u1.y & 0xffff0000u);
            a[4] += __uint_as_float(u1.z << 16);
            a[5] += __uint_as_float(u1.z & 0xffff0000u);
            a[6] += __uint_as_float(u1.w << 16);
            a[7] += __uint_as_float(u1.w & 0xffff0000u);
        }

#pragma unroll
        for (int j = 0; j < 8; j++) {
            a[j] += __shfl_xor(a[j], 16, 64);
            a[j] += __shfl_xor(a[j], 32, 64);
        }

        if (q == 0) {
            const float inv = 1.f / fmaxf((float)(e - s), 1.f);
            float4 o1, o2;
            o1.x = fmaxf(a[0] * inv, 0.f); o1.y = fmaxf(a[1] * inv, 0.f);
            o1.z = fmaxf(a[2] * inv, 0.f); o1.w = fmaxf(a[3] * inv, 0.f);
            o2.x = fmaxf(a[4] * inv, 0.f); o2.y = fmaxf(a[5] * inv, 0.f);
            o2.z = fmaxf(a[6] * inv, 0.f); o2.w = fmaxf(a[7] * inv, 0.f);
            float* op = outp + (size_t)node * 128 + l16 * 8;
            *(float4*)op = o1;
            *(float4*)(op + 4) = o2;
        }
    }
}

// ---------------- post MLP (128->128, 128->40) + log_softmax ----------------
__global__ __launch_bounds__(256) void postmlp(const float* __restrict__ X,
                                               const float* __restrict__ Wp1t,
                                               const float* __restrict__ bp1,
                                               const float* __restrict__ Wp2t,  // [128][64] padded
                                               const float* __restrict__ bp2,
                                               float* __restrict__ Out) {
    __shared__ float xT[128 * 36];
    __shared__ float hT[128 * 36];
    const int t = threadIdx.x;
    const int base = blockIdx.x * 32;

#pragma unroll
    for (int i = 0; i < 4; i++) {
        int f = (i * 256 + t) * 4;
        int row = f >> 7, col = f & 127;
        const float4 v = *(const float4*)(X + (size_t)(base + row) * 128 + col);
        xT[(col + 0) * 36 + row] = v.x;
        xT[(col + 1) * 36 + row] = v.y;
        xT[(col + 2) * 36 + row] = v.z;
        xT[(col + 3) * 36 + row] = v.w;
    }
    __syncthreads();

    {
        const int rg = t >> 5, cg = t & 31;
        float acc[4][4] = {};
#pragma unroll 4
        for (int k = 0; k < 128; k++) {
            const float4 a = *(const float4*)(&xT[k * 36 + rg * 4]);
            const float4 wv = *(const float4*)(Wp1t + k * 128 + cg * 4);
            const float av[4] = {a.x, a.y, a.z, a.w};
            const float wl[4] = {wv.x, wv.y, wv.z, wv.w};
#pragma unroll
            for (int r = 0; r < 4; r++)
#pragma unroll
                for (int c = 0; c < 4; c++) acc[r][c] = fmaf(av[r], wl[c], acc[r][c]);
        }
        const float4 bv = *(const float4*)(bp1 + cg * 4);
        const float bl[4] = {bv.x, bv.y, bv.z, bv.w};
#pragma unroll
        for (int r = 0; r < 4; r++)
#pragma unroll
            for (int c = 0; c < 4; c++)
                hT[(cg * 4 + c) * 36 + rg * 4 + r] = acc[r][c] + bl[c];
    }
    __syncthreads();

    {
        const int rg2 = t >> 4, cg2 = t & 15;
        const bool valid = (cg2 < 10);
        float acc[2][4] = {};
#pragma unroll 4
        for (int k = 0; k < 128; k++) {
            const float2 a = *(const float2*)(&hT[k * 36 + rg2 * 2]);
            const float4 wv = *(const float4*)(Wp2t + k * 64 + cg2 * 4);
            const float wl[4] = {wv.x, wv.y, wv.z, wv.w};
#pragma unroll
            for (int c = 0; c < 4; c++) {
                acc[0][c] = fmaf(a.x, wl[c], acc[0][c]);
                acc[1][c] = fmaf(a.y, wl[c], acc[1][c]);
            }
        }
        float bl[4] = {0.f, 0.f, 0.f, 0.f};
        if (valid) {
#pragma unroll
            for (int c = 0; c < 4; c++) bl[c] = bp2[cg2 * 4 + c];
        }
#pragma unroll
        for (int r = 0; r < 2; r++) {
            float v[4];
#pragma unroll
            for (int c = 0; c < 4; c++) v[c] = acc[r][c] + bl[c];
            float m = valid ? fmaxf(fmaxf(v[0], v[1]), fmaxf(v[2], v[3])) : -1e30f;
#pragma unroll
            for (int msk = 8; msk >= 1; msk >>= 1) m = fmaxf(m, __shfl_xor(m, msk, 64));
            float se = 0.f;
            if (valid) {
#pragma unroll
                for (int c = 0; c < 4; c++) se += expf(v[c] - m);
            }
#pragma unroll
            for (int msk = 8; msk >= 1; msk >>= 1) se += __shfl_xor(se, msk, 64);
            const float lse = logf(se);
            if (valid) {
                float4 o;
                o.x = v[0] - m - lse; o.y = v[1] - m - lse;
                o.z = v[2] - m - lse; o.w = v[3] - m - lse;
                const int row = base + rg2 * 2 + r;
                *(float4*)(Out + (size_t)row * 40 + cg2 * 4) = o;
            }
        }
    }
}

extern "C" void kernel_launch(void* const* d_in, const int* in_sizes, int n_in,
                              void* d_out, int out_size, void* d_ws, size_t ws_size,
                              hipStream_t stream) {
    const float* x   = (const float*)d_in[0];
    const int*   ei  = (const int*)d_in[1];
    const float* W0  = (const float*)d_in[2];
    const float* b0  = (const float*)d_in[3];
    const float* W1  = (const float*)d_in[4];
    const float* b1  = (const float*)d_in[5];
    const float* W2  = (const float*)d_in[6];
    const float* b2  = (const float*)d_in[7];
    const float* Wp1 = (const float*)d_in[8];
    const float* bp1 = (const float*)d_in[9];
    const float* Wp2 = (const float*)d_in[10];
    const float* bp2 = (const float*)d_in[11];
    float* out = (float*)d_out;

    const int E = in_sizes[1] / 2;
    const int* srcv = ei;
    const int* dstv = ei + E;

    char* w = (char*)d_ws;
    auto alloc = [&](size_t sz) {
        char* p = w;
        w += (sz + 255) & ~(size_t)255;
        return p;
    };
    ushort16* H   = (ushort16*)alloc(sizeof(ushort16) * (size_t)NN * 128);  // bf16 h table
    float* B1     = (float*)alloc(sizeof(float) * (size_t)NN * 128);        // f32 agg out
    uint32* ebuf  = (uint32*)alloc(sizeof(uint32) * (size_t)NB * CAP);
    int*   colv   = (int*)alloc(sizeof(int) * (size_t)E);
    int*   rowptr = (int*)alloc(sizeof(int) * (NN + 1));
    int*   cursor = (int*)alloc(sizeof(int) * NB);
    int*   bstart = (int*)alloc(sizeof(int) * NB);
    float* Wt0    = (float*)alloc(sizeof(float) * 128 * 128);
    float* Wt1    = (float*)alloc(sizeof(float) * 128 * 128);
    float* Wt2    = (float*)alloc(sizeof(float) * 128 * 128);
    float* Wtp1   = (float*)alloc(sizeof(float) * 128 * 128);
    float* Wtp2   = (float*)alloc(sizeof(float) * 128 * 64);

    transpose_w<<<64, 256, 0, stream>>>(W0, Wt0, 128, 128);
    transpose_w<<<64, 256, 0, stream>>>(W1, Wt1, 128, 128);
    transpose_w<<<64, 256, 0, stream>>>(W2, Wt2, 128, 128);
    transpose_w<<<64, 256, 0, stream>>>(Wp1, Wtp1, 128, 128);
    transpose_w<<<32, 256, 0, stream>>>(Wp2, Wtp2, 40, 64);

    // CSR build (bucketed counting sort)
    hipMemsetAsync(cursor, 0, sizeof(int) * NB, stream);
    csr_k1<<<(E + CHUNK - 1) / CHUNK, 256, 0, stream>>>(srcv, dstv, E, cursor, ebuf);
    scanb_k<<<1, 512, 0, stream>>>(cursor, bstart);
    csr_k2<<<(NN + NLOC - 1) / NLOC, 256, 0, stream>>>(ebuf, cursor, bstart, rowptr, colv, E);

    // 3 SAGE layers
    lin_norm<<<NN / 32, 256, 0, stream>>>(x, Wt0, b0, H);
    agg_k<<<4096, 256, 0, stream>>>(H, rowptr, colv, B1);
    lin_norm<<<NN / 32, 256, 0, stream>>>(B1, Wt1, b1, H);
    agg_k<<<4096, 256, 0, stream>>>(H, rowptr, colv, B1);
    lin_norm<<<NN / 32, 256, 0, stream>>>(B1, Wt2, b2, H);
    agg_k<<<4096, 256, 0, stream>>>(H, rowptr, colv, B1);

    // post-MLP + log_softmax
    postmlp<<<NN / 32, 256, 0, stream>>>(B1, Wtp1, bp1, Wtp2, bp2, out);
}

// Round 4
// 566.865 us; speedup vs baseline: 2.8857x; 1.2323x over previous
//
#include <hip/hip_runtime.h>
#include <cmath>

#define NN 100000
#define NB 512          // dst buckets
#define NLOC 196        // nodes per bucket
#define CAP 7168        // per-bucket edge capacity
#define CHUNK 8192      // edges per csr_k1 block

typedef unsigned int uint32;
typedef unsigned short ushort16;
typedef __attribute__((ext_vector_type(8))) short short8;
typedef __attribute__((ext_vector_type(4))) float f32x4;

__device__ __forceinline__ ushort16 f2bf(float f) {
    uint32 b = __float_as_uint(f);
    uint32 r = (b + 0x7FFFu + ((b >> 16) & 1u)) >> 16;   // RNE
    return (ushort16)r;
}

// ---------------- f32 -> bf16 convert (n multiple of 4) ----------------
__global__ void conv_bf16(const float4* __restrict__ in, uint2* __restrict__ out, int n4) {
    int i = blockIdx.x * 256 + threadIdx.x;
    if (i >= n4) return;
    const float4 v = in[i];
    ushort16 o[4] = {f2bf(v.x), f2bf(v.y), f2bf(v.z), f2bf(v.w)};
    out[i] = *(uint2*)o;
}

// Wp2 [40][128] f32 -> [48][128] bf16 zero-padded rows
__global__ void conv_pad_w2(const float* __restrict__ in, ushort16* __restrict__ out) {
    int i = blockIdx.x * 256 + threadIdx.x;     // 1536 quads
    if (i >= 48 * 128 / 4) return;
    int e = i * 4;
    int j = e >> 7, k = e & 127;
    ushort16 o[4];
#pragma unroll
    for (int c = 0; c < 4; c++) o[c] = (j < 40) ? f2bf(in[j * 128 + k + c]) : (ushort16)0;
    *(uint2*)(out + e) = *(uint2*)o;
}

// ---------------- CSR build: pass 1 — bucket partition ----------------
__global__ __launch_bounds__(256) void csr_k1(const int* __restrict__ srcv,
                                              const int* __restrict__ dstv, int E,
                                              int* __restrict__ cursor,
                                              uint32* __restrict__ ebuf) {
    __shared__ int lhist[NB];
    __shared__ int lbase[NB];
    __shared__ int lcnt[NB];
    const int t = threadIdx.x;
    const int e0 = blockIdx.x * CHUNK;
    const int e1 = min(e0 + CHUNK, E);

    for (int i = t; i < NB; i += 256) { lhist[i] = 0; lcnt[i] = 0; }
    __syncthreads();
    for (int i = e0 + t; i < e1; i += 256)
        atomicAdd(&lhist[dstv[i] / NLOC], 1);
    __syncthreads();
    for (int i = t; i < NB; i += 256)
        lbase[i] = lhist[i] ? atomicAdd(&cursor[i], lhist[i]) : 0;
    __syncthreads();
    for (int i = e0 + t; i < e1; i += 256) {
        const int d = dstv[i];
        const int s = srcv[i];
        const int b = d / NLOC;
        const int pos = lbase[b] + atomicAdd(&lcnt[b], 1);
        if (pos < CAP)
            ebuf[(size_t)b * CAP + pos] = (uint32)s | ((uint32)(d - b * NLOC) << 17);
    }
}

__global__ __launch_bounds__(512) void scanb_k(const int* __restrict__ cursor,
                                               int* __restrict__ bstart) {
    __shared__ int sd[512];
    const int t = threadIdx.x;
    const int v = cursor[t];
    sd[t] = v;
    __syncthreads();
    for (int off = 1; off < 512; off <<= 1) {
        int x = (t >= off) ? sd[t - off] : 0;
        __syncthreads();
        sd[t] += x;
        __syncthreads();
    }
    bstart[t] = sd[t] - v;   // exclusive
}

__global__ __launch_bounds__(256) void csr_k2(const uint32* __restrict__ ebuf,
                                              const int* __restrict__ cursor,
                                              const int* __restrict__ bstart,
                                              int* __restrict__ rowptr,
                                              int* __restrict__ colv, int Etot) {
    __shared__ int sd[256];
    __shared__ int loc[256];
    __shared__ int cnt[256];
    const int b = blockIdx.x;
    const int t = threadIdx.x;
    const int n = cursor[b];
    const int n0 = b * NLOC;
    const int nloc = min(NN - n0, NLOC);
    const int bst = bstart[b];
    const uint32* seg = ebuf + (size_t)b * CAP;

    sd[t] = 0; cnt[t] = 0;
    __syncthreads();
    for (int i = t; i < n; i += 256)
        atomicAdd(&sd[seg[i] >> 17], 1);
    __syncthreads();
    const int v = sd[t];
    __syncthreads();
    for (int off = 1; off < 256; off <<= 1) {
        int x = (t >= off) ? sd[t - off] : 0;
        __syncthreads();
        sd[t] += x;
        __syncthreads();
    }
    loc[t] = sd[t] - v;
    __syncthreads();
    if (t < nloc) rowptr[n0 + t] = bst + loc[t];
    if (b == 0 && t == 0) rowptr[NN] = Etot;
    for (int i = t; i < n; i += 256) {
        const uint32 p = seg[i];
        const int l = p >> 17;
        const int src = p & 0x1FFFF;
        const int pos = atomicAdd(&cnt[l], 1);
        colv[bst + loc[l] + pos] = src;
    }
}

// ---------------- MFMA projection + L2 normalize ----------------
// 4 waves, 16 rows/wave, 64 rows/block. Y[row][col] = normalize(X@W.T + b), bf16 out.
// Swapped mfma(w,x): lane holds row rbase+(l&15), cols j*16 + (l>>4)*4 + r.
__global__ __launch_bounds__(256) void lin_mfma(const ushort16* __restrict__ Xb,
                                                const ushort16* __restrict__ Wb,
                                                const float* __restrict__ bias,
                                                ushort16* __restrict__ Yb) {
    const int t = threadIdx.x;
    const int w = t >> 6;
    const int l = t & 63;
    const int l15 = l & 15, lh = l >> 4;
    const int rbase = blockIdx.x * 64 + w * 16;
    int arow = rbase + l15;
    if (arow >= NN) arow = NN - 1;

    f32x4 acc[8];
#pragma unroll
    for (int j = 0; j < 8; j++) acc[j] = (f32x4){0.f, 0.f, 0.f, 0.f};

    const ushort16* ap = Xb + (size_t)arow * 128 + lh * 8;
#pragma unroll
    for (int kk = 0; kk < 4; kk++) {
        const short8 a = *(const short8*)(ap + kk * 32);
#pragma unroll
        for (int j = 0; j < 8; j++) {
            const short8 b = *(const short8*)(Wb + (size_t)(j * 16 + l15) * 128 + kk * 32 + lh * 8);
            acc[j] = __builtin_amdgcn_mfma_f32_16x16x32_bf16(b, a, acc[j], 0, 0, 0);
        }
    }

    float v[8][4];
    float ssq = 0.f;
#pragma unroll
    for (int j = 0; j < 8; j++) {
        const float4 bv = *(const float4*)(bias + j * 16 + lh * 4);
        v[j][0] = acc[j][0] + bv.x;
        v[j][1] = acc[j][1] + bv.y;
        v[j][2] = acc[j][2] + bv.z;
        v[j][3] = acc[j][3] + bv.w;
        ssq += v[j][0] * v[j][0] + v[j][1] * v[j][1] + v[j][2] * v[j][2] + v[j][3] * v[j][3];
    }
    ssq += __shfl_xor(ssq, 16, 64);
    ssq += __shfl_xor(ssq, 32, 64);
    const float sc = 1.f / fmaxf(sqrtf(ssq), 1e-12f);

    const int row = rbase + l15;
    if (row < NN) {
        ushort16* yp = Yb + (size_t)row * 128;
#pragma unroll
        for (int j = 0; j < 8; j++) {
            ushort16 o[4] = {f2bf(v[j][0] * sc), f2bf(v[j][1] * sc),
                             f2bf(v[j][2] * sc), f2bf(v[j][3] * sc)};
            *(uint2*)(yp + j * 16 + lh * 4) = *(uint2*)o;
        }
    }
}

// ---------------- CSR mean-aggregate + ReLU (bf16 gather, bf16 out) ----------------
__global__ __launch_bounds__(256) void agg_k(const ushort16* __restrict__ hp,
                                             const int* __restrict__ rowptr,
                                             const int* __restrict__ colv,
                                             ushort16* __restrict__ outp) {
    const int lane = threadIdx.x & 63;
    const int q = lane >> 4;
    const int l16 = lane & 15;
    const int wid = blockIdx.x * 4 + (threadIdx.x >> 6);
    const int nw = gridDim.x * 4;

    for (int node = wid; node < NN; node += nw) {
        const int s = rowptr[node], e = rowptr[node + 1];
        float a[8] = {};
        const ushort16* bp = hp + (size_t)l16 * 8;

        int i = s + q;
        for (; i + 4 < e; i += 8) {
            const int c1 = colv[i];
            const int c2 = colv[i + 4];
            const uint4 u1 = *(const uint4*)(bp + (size_t)c1 * 128);
            const uint4 u2 = *(const uint4*)(bp + (size_t)c2 * 128);
            a[0] += __uint_as_float(u1.x << 16) + __uint_as_float(u2.x << 16);
            a[1] += __uint_as_float(u1.x & 0xffff0000u) + __uint_as_float(u2.x & 0xffff0000u);
            a[2] += __uint_as_float(u1.y << 16) + __uint_as_float(u2.y << 16);
            a[3] += __uint_as_float(u1.y & 0xffff0000u) + __uint_as_float(u2.y & 0xffff0000u);
            a[4] += __uint_as_float(u1.z << 16) + __uint_as_float(u2.z << 16);
            a[5] += __uint_as_float(u1.z & 0xffff0000u) + __uint_as_float(u2.z & 0xffff0000u);
            a[6] += __uint_as_float(u1.w << 16) + __uint_as_float(u2.w << 16);
            a[7] += __uint_as_float(u1.w & 0xffff0000u) + __uint_as_float(u2.w & 0xffff0000u);
        }
        if (i < e) {
            const int c1 = colv[i];
            const uint4 u1 = *(const uint4*)(bp + (size_t)c1 * 128);
            a[0] += __uint_as_float(u1.x << 16);
            a[1] += __uint_as_float(u1.x & 0xffff0000u);
            a[2] += __uint_as_float(u1.y << 16);
            a[3] += __uint_as_float(u1.y & 0xffff0000u);
            a[4] += __uint_as_float(u1.z << 16);
            a[5] += __uint_as_float(u1.z & 0xffff0000u);
            a[6] += __uint_as_float(u1.w << 16);
            a[7] += __uint_as_float(u1.w & 0xffff0000u);
        }

#pragma unroll
        for (int j = 0; j < 8; j++) {
            a[j] += __shfl_xor(a[j], 16, 64);
            a[j] += __shfl_xor(a[j], 32, 64);
        }

        if (q == 0) {
            const float inv = 1.f / fmaxf((float)(e - s), 1.f);
            ushort16 o[8];
#pragma unroll
            for (int j = 0; j < 8; j++) o[j] = f2bf(fmaxf(a[j] * inv, 0.f));
            *(uint4*)(outp + (size_t)node * 128 + l16 * 8) = *(uint4*)o;
        }
    }
}

// ---------------- post MLP (MFMA 128->128, 128->40) + log_softmax ----------------
__global__ __launch_bounds__(256) void post_mfma(const ushort16* __restrict__ Bb,
                                                 const ushort16* __restrict__ W1b,
                                                 const float* __restrict__ bp1,
                                                 const ushort16* __restrict__ W2b,  // [48][128] padded
                                                 const float* __restrict__ bp2,
                                                 float* __restrict__ Out) {
    __shared__ ushort16 hls[64 * 128];   // h1 bf16, XOR-swizzled
    const int t = threadIdx.x;
    const int w = t >> 6;
    const int l = t & 63;
    const int l15 = l & 15, lh = l >> 4;
    const int rl = w * 16 + l15;               // local row 0..63
    const int rbase = blockIdx.x * 64 + w * 16;
    int arow = rbase + l15;
    if (arow >= NN) arow = NN - 1;

    // ---- stage 1: h1 = X @ Wp1.T + bp1 ----
    {
        f32x4 acc[8];
#pragma unroll
        for (int j = 0; j < 8; j++) acc[j] = (f32x4){0.f, 0.f, 0.f, 0.f};
        const ushort16* ap = Bb + (size_t)arow * 128 + lh * 8;
#pragma unroll
        for (int kk = 0; kk < 4; kk++) {
            const short8 a = *(const short8*)(ap + kk * 32);
#pragma unroll
            for (int j = 0; j < 8; j++) {
                const short8 b = *(const short8*)(W1b + (size_t)(j * 16 + l15) * 128 + kk * 32 + lh * 8);
                acc[j] = __builtin_amdgcn_mfma_f32_16x16x32_bf16(b, a, acc[j], 0, 0, 0);
            }
        }
        // write h1 (bf16) to LDS, swizzled: byte = rl*256 + j*32 + lh*8, ^((rl&7)<<4)
        char* lp = (char*)hls;
#pragma unroll
        for (int j = 0; j < 8; j++) {
            const float4 bv = *(const float4*)(bp1 + j * 16 + lh * 4);
            ushort16 o[4] = {f2bf(acc[j][0] + bv.x), f2bf(acc[j][1] + bv.y),
                             f2bf(acc[j][2] + bv.z), f2bf(acc[j][3] + bv.w)};
            const int byte = (rl * 256 + j * 32 + lh * 8) ^ ((rl & 7) << 4);
            *(uint2*)(lp + byte) = *(uint2*)o;
        }
    }
    __syncthreads();

    // ---- stage 2: logits = h1 @ Wp2.T + bp2 (48-padded), log_softmax ----
    {
        f32x4 acc[3];
#pragma unroll
        for (int j = 0; j < 3; j++) acc[j] = (f32x4){0.f, 0.f, 0.f, 0.f};
        const char* lp = (const char*)hls;
#pragma unroll
        for (int kk = 0; kk < 4; kk++) {
            const int byte = (rl * 256 + kk * 64 + lh * 16) ^ ((rl & 7) << 4);
            const short8 a = *(const short8*)(lp + byte);
#pragma unroll
            for (int j = 0; j < 3; j++) {
                const short8 b = *(const short8*)(W2b + (size_t)(j * 16 + l15) * 128 + kk * 32 + lh * 8);
                acc[j] = __builtin_amdgcn_mfma_f32_16x16x32_bf16(b, a, acc[j], 0, 0, 0);
            }
        }

        float v[3][4];
        float m = -1e30f;
#pragma unroll
        for (int j = 0; j < 3; j++) {
            const bool val = (j < 2) || (lh < 2);
            if (val) {
                const float4 bv = *(const float4*)(bp2 + j * 16 + lh * 4);
                v[j][0] = acc[j][0] + bv.x;
                v[j][1] = acc[j][1] + bv.y;
                v[j][2] = acc[j][2] + bv.z;
                v[j][3] = acc[j][3] + bv.w;
#pragma unroll
                for (int r = 0; r < 4; r++) m = fmaxf(m, v[j][r]);
            } else {
#pragma unroll
                for (int r = 0; r < 4; r++) v[j][r] = -1e30f;
            }
        }
        m = fmaxf(m, __shfl_xor(m, 16, 64));
        m = fmaxf(m, __shfl_xor(m, 32, 64));
        float se = 0.f;
#pragma unroll
        for (int j = 0; j < 3; j++)
#pragma unroll
            for (int r = 0; r < 4; r++) se += expf(v[j][r] - m);
        se += __shfl_xor(se, 16, 64);
        se += __shfl_xor(se, 32, 64);
        const float lse = logf(se) + m;

        const int row = rbase + l15;
        if (row < NN) {
            float* op = Out + (size_t)row * 40;
#pragma unroll
            for (int j = 0; j < 3; j++) {
                if (j == 2 && lh >= 2) continue;
                float4 o;
                o.x = v[j][0] - lse; o.y = v[j][1] - lse;
                o.z = v[j][2] - lse; o.w = v[j][3] - lse;
                *(float4*)(op + j * 16 + lh * 4) = o;
            }
        }
    }
}

extern "C" void kernel_launch(void* const* d_in, const int* in_sizes, int n_in,
                              void* d_out, int out_size, void* d_ws, size_t ws_size,
                              hipStream_t stream) {
    const float* x   = (const float*)d_in[0];
    const int*   ei  = (const int*)d_in[1];
    const float* W0  = (const float*)d_in[2];
    const float* b0  = (const float*)d_in[3];
    const float* W1  = (const float*)d_in[4];
    const float* b1  = (const float*)d_in[5];
    const float* W2  = (const float*)d_in[6];
    const float* b2  = (const float*)d_in[7];
    const float* Wp1 = (const float*)d_in[8];
    const float* bp1 = (const float*)d_in[9];
    const float* Wp2 = (const float*)d_in[10];
    const float* bp2 = (const float*)d_in[11];
    float* out = (float*)d_out;

    const int E = in_sizes[1] / 2;
    const int* srcv = ei;
    const int* dstv = ei + E;

    char* w = (char*)d_ws;
    auto alloc = [&](size_t sz) {
        char* p = w;
        w += (sz + 255) & ~(size_t)255;
        return p;
    };
    ushort16* Xb  = (ushort16*)alloc(sizeof(ushort16) * (size_t)NN * 128);  // x bf16
    ushort16* H   = (ushort16*)alloc(sizeof(ushort16) * (size_t)NN * 128);  // lin out bf16
    ushort16* Bb  = (ushort16*)alloc(sizeof(ushort16) * (size_t)NN * 128);  // agg out bf16
    uint32* ebuf  = (uint32*)alloc(sizeof(uint32) * (size_t)NB * CAP);
    int*   colv   = (int*)alloc(sizeof(int) * (size_t)E);
    int*   rowptr = (int*)alloc(sizeof(int) * (NN + 1));
    int*   cursor = (int*)alloc(sizeof(int) * NB);
    int*   bstart = (int*)alloc(sizeof(int) * NB);
    ushort16* Wb0 = (ushort16*)alloc(sizeof(ushort16) * 128 * 128);
    ushort16* Wb1 = (ushort16*)alloc(sizeof(ushort16) * 128 * 128);
    ushort16* Wb2 = (ushort16*)alloc(sizeof(ushort16) * 128 * 128);
    ushort16* Wb3 = (ushort16*)alloc(sizeof(ushort16) * 128 * 128);
    ushort16* Wb4 = (ushort16*)alloc(sizeof(ushort16) * 48 * 128);

    // converts
    conv_bf16<<<(NN * 128 / 4 + 255) / 256, 256, 0, stream>>>((const float4*)x, (uint2*)Xb, NN * 128 / 4);
    conv_bf16<<<16, 256, 0, stream>>>((const float4*)W0, (uint2*)Wb0, 4096);
    conv_bf16<<<16, 256, 0, stream>>>((const float4*)W1, (uint2*)Wb1, 4096);
    conv_bf16<<<16, 256, 0, stream>>>((const float4*)W2, (uint2*)Wb2, 4096);
    conv_bf16<<<16, 256, 0, stream>>>((const float4*)Wp1, (uint2*)Wb3, 4096);
    conv_pad_w2<<<6, 256, 0, stream>>>(Wp2, Wb4);

    // CSR build (bucketed counting sort)
    hipMemsetAsync(cursor, 0, sizeof(int) * NB, stream);
    csr_k1<<<(E + CHUNK - 1) / CHUNK, 256, 0, stream>>>(srcv, dstv, E, cursor, ebuf);
    scanb_k<<<1, 512, 0, stream>>>(cursor, bstart);
    csr_k2<<<(NN + NLOC - 1) / NLOC, 256, 0, stream>>>(ebuf, cursor, bstart, rowptr, colv, E);

    const int nlb = (NN + 63) / 64;   // 1563
    // 3 SAGE layers
    lin_mfma<<<nlb, 256, 0, stream>>>(Xb, Wb0, b0, H);
    agg_k<<<4096, 256, 0, stream>>>(H, rowptr, colv, Bb);
    lin_mfma<<<nlb, 256, 0, stream>>>(Bb, Wb1, b1, H);
    agg_k<<<4096, 256, 0, stream>>>(H, rowptr, colv, Bb);
    lin_mfma<<<nlb, 256, 0, stream>>>(Bb, Wb2, b2, H);
    agg_k<<<4096, 256, 0, stream>>>(H, rowptr, colv, Bb);

    // post-MLP + log_softmax
    post_mfma<<<nlb, 256, 0, stream>>>(Bb, Wb3, bp1, Wb4, bp2, out);
}

// Round 5
// 520.475 us; speedup vs baseline: 3.1429x; 1.0891x over previous
//
#include <hip/hip_runtime.h>
#include <cmath>

#define NN 100000
#define NB 512          // dst buckets
#define NLOC 196        // nodes per bucket
#define CAP 7168        // per-bucket edge capacity
#define CHUNK 8192      // edges per csr_k1 block

typedef unsigned int uint32;
typedef unsigned short ushort16;
typedef __attribute__((ext_vector_type(8))) short short8;
typedef __attribute__((ext_vector_type(4))) float f32x4;

__device__ __forceinline__ ushort16 f2bf(float f) {
    uint32 b = __float_as_uint(f);
    uint32 r = (b + 0x7FFFu + ((b >> 16) & 1u)) >> 16;   // RNE
    return (ushort16)r;
}

// ---------------- f32 -> bf16 convert (n multiple of 4) ----------------
__global__ void conv_bf16(const float4* __restrict__ in, uint2* __restrict__ out, int n4) {
    int i = blockIdx.x * 256 + threadIdx.x;
    if (i >= n4) return;
    const float4 v = in[i];
    ushort16 o[4] = {f2bf(v.x), f2bf(v.y), f2bf(v.z), f2bf(v.w)};
    out[i] = *(uint2*)o;
}

// Wp2 [40][128] f32 -> [48][128] bf16 zero-padded rows
__global__ void conv_pad_w2(const float* __restrict__ in, ushort16* __restrict__ out) {
    int i = blockIdx.x * 256 + threadIdx.x;     // 1536 quads
    if (i >= 48 * 128 / 4) return;
    int e = i * 4;
    int j = e >> 7, k = e & 127;
    ushort16 o[4];
#pragma unroll
    for (int c = 0; c < 4; c++) o[c] = (j < 40) ? f2bf(in[j * 128 + k + c]) : (ushort16)0;
    *(uint2*)(out + e) = *(uint2*)o;
}

// ---------------- CSR build: pass 1 — bucket partition ----------------
__global__ __launch_bounds__(256) void csr_k1(const int* __restrict__ srcv,
                                              const int* __restrict__ dstv, int E,
                                              int* __restrict__ cursor,
                                              uint32* __restrict__ ebuf) {
    __shared__ int lhist[NB];
    __shared__ int lbase[NB];
    __shared__ int lcnt[NB];
    const int t = threadIdx.x;
    const int e0 = blockIdx.x * CHUNK;
    const int e1 = min(e0 + CHUNK, E);

    for (int i = t; i < NB; i += 256) { lhist[i] = 0; lcnt[i] = 0; }
    __syncthreads();
    for (int i = e0 + t; i < e1; i += 256)
        atomicAdd(&lhist[dstv[i] / NLOC], 1);
    __syncthreads();
    for (int i = t; i < NB; i += 256)
        lbase[i] = lhist[i] ? atomicAdd(&cursor[i], lhist[i]) : 0;
    __syncthreads();
    for (int i = e0 + t; i < e1; i += 256) {
        const int d = dstv[i];
        const int s = srcv[i];
        const int b = d / NLOC;
        const int pos = lbase[b] + atomicAdd(&lcnt[b], 1);
        if (pos < CAP)
            ebuf[(size_t)b * CAP + pos] = (uint32)s | ((uint32)(d - b * NLOC) << 17);
    }
}

__global__ __launch_bounds__(512) void scanb_k(const int* __restrict__ cursor,
                                               int* __restrict__ bstart) {
    __shared__ int sd[512];
    const int t = threadIdx.x;
    const int v = cursor[t];
    sd[t] = v;
    __syncthreads();
    for (int off = 1; off < 512; off <<= 1) {
        int x = (t >= off) ? sd[t - off] : 0;
        __syncthreads();
        sd[t] += x;
        __syncthreads();
    }
    bstart[t] = sd[t] - v;   // exclusive
}

__global__ __launch_bounds__(256) void csr_k2(const uint32* __restrict__ ebuf,
                                              const int* __restrict__ cursor,
                                              const int* __restrict__ bstart,
                                              int* __restrict__ rowptr,
                                              int* __restrict__ colv, int Etot) {
    __shared__ int sd[256];
    __shared__ int loc[256];
    __shared__ int cnt[256];
    const int b = blockIdx.x;
    const int t = threadIdx.x;
    const int n = cursor[b];
    const int n0 = b * NLOC;
    const int nloc = min(NN - n0, NLOC);
    const int bst = bstart[b];
    const uint32* seg = ebuf + (size_t)b * CAP;

    sd[t] = 0; cnt[t] = 0;
    __syncthreads();
    for (int i = t; i < n; i += 256)
        atomicAdd(&sd[seg[i] >> 17], 1);
    __syncthreads();
    const int v = sd[t];
    __syncthreads();
    for (int off = 1; off < 256; off <<= 1) {
        int x = (t >= off) ? sd[t - off] : 0;
        __syncthreads();
        sd[t] += x;
        __syncthreads();
    }
    loc[t] = sd[t] - v;
    __syncthreads();
    if (t < nloc) rowptr[n0 + t] = bst + loc[t];
    if (b == 0 && t == 0) rowptr[NN] = Etot;
    for (int i = t; i < n; i += 256) {
        const uint32 p = seg[i];
        const int l = p >> 17;
        const int src = p & 0x1FFFF;
        const int pos = atomicAdd(&cnt[l], 1);
        colv[bst + loc[l] + pos] = src;
    }
}

// ---------------- MFMA projection + L2 normalize ----------------
// 4 waves, 16 rows/wave, 64 rows/block; W staged in LDS in fragment layout.
__global__ __launch_bounds__(256) void lin_mfma(const ushort16* __restrict__ Xb,
                                                const ushort16* __restrict__ Wb,
                                                const float* __restrict__ bias,
                                                ushort16* __restrict__ Yb) {
    __shared__ short8 wls[2048];      // [j][kk][lane] 16B fragments = 32 KB
    const int t = threadIdx.x;
    const int l = t & 63;
    const int l15 = l & 15, lh = l >> 4;
    const int rbase = blockIdx.x * 64 + (t >> 6) * 16;
    int arow = rbase + l15;
    if (arow >= NN) arow = NN - 1;

    // stage W fragments: idx -> j=idx>>8, kk=(idx>>6)&3, lane=idx&63
#pragma unroll
    for (int it = 0; it < 8; it++) {
        const int idx = it * 256 + t;
        const int j = idx >> 8, kk = (idx >> 6) & 3, ll = idx & 63;
        wls[idx] = *(const short8*)(Wb + (size_t)(j * 16 + (ll & 15)) * 128 + kk * 32 + (ll >> 4) * 8);
    }

    // hoist A fragments (one row per lane-of-16, 64B)
    const ushort16* ap = Xb + (size_t)arow * 128 + lh * 8;
    short8 a[4];
#pragma unroll
    for (int kk = 0; kk < 4; kk++) a[kk] = *(const short8*)(ap + kk * 32);

    __syncthreads();

    f32x4 acc[8];
#pragma unroll
    for (int j = 0; j < 8; j++) acc[j] = (f32x4){0.f, 0.f, 0.f, 0.f};

#pragma unroll
    for (int kk = 0; kk < 4; kk++)
#pragma unroll
        for (int j = 0; j < 8; j++)
            acc[j] = __builtin_amdgcn_mfma_f32_16x16x32_bf16(wls[j * 256 + kk * 64 + l], a[kk], acc[j], 0, 0, 0);

    float v[8][4];
    float ssq = 0.f;
#pragma unroll
    for (int j = 0; j < 8; j++) {
        const float4 bv = *(const float4*)(bias + j * 16 + lh * 4);
        v[j][0] = acc[j][0] + bv.x;
        v[j][1] = acc[j][1] + bv.y;
        v[j][2] = acc[j][2] + bv.z;
        v[j][3] = acc[j][3] + bv.w;
        ssq += v[j][0] * v[j][0] + v[j][1] * v[j][1] + v[j][2] * v[j][2] + v[j][3] * v[j][3];
    }
    ssq += __shfl_xor(ssq, 16, 64);
    ssq += __shfl_xor(ssq, 32, 64);
    const float sc = 1.f / fmaxf(sqrtf(ssq), 1e-12f);

    const int row = rbase + l15;
    if (row < NN) {
        ushort16* yp = Yb + (size_t)row * 128;
#pragma unroll
        for (int j = 0; j < 8; j++) {
            ushort16 o[4] = {f2bf(v[j][0] * sc), f2bf(v[j][1] * sc),
                             f2bf(v[j][2] * sc), f2bf(v[j][3] * sc)};
            *(uint2*)(yp + j * 16 + lh * 4) = *(uint2*)o;
        }
    }
}

// ---------------- CSR mean-aggregate + ReLU (bf16 gather, 4-deep) ----------------
__global__ __launch_bounds__(256) void agg_k(const ushort16* __restrict__ hp,
                                             const int* __restrict__ rowptr,
                                             const int* __restrict__ colv,
                                             ushort16* __restrict__ outp) {
    const int lane = threadIdx.x & 63;
    const int q = lane >> 4;
    const int l16 = lane & 15;
    const int wid = blockIdx.x * 4 + (threadIdx.x >> 6);
    const int nw = gridDim.x * 4;

    for (int node = wid; node < NN; node += nw) {
        const int s = rowptr[node], e = rowptr[node + 1];
        float a[8] = {};
        const ushort16* bp = hp + (size_t)l16 * 8;

        int i = s + q;
        // 4-deep: rows i, i+4, i+8, i+12 in flight per quarter-wave lane
        for (; i + 12 < e; i += 16) {
            const int c0 = colv[i];
            const int c1 = colv[i + 4];
            const int c2 = colv[i + 8];
            const int c3 = colv[i + 12];
            const uint4 u0 = *(const uint4*)(bp + (size_t)c0 * 128);
            const uint4 u1 = *(const uint4*)(bp + (size_t)c1 * 128);
            const uint4 u2 = *(const uint4*)(bp + (size_t)c2 * 128);
            const uint4 u3 = *(const uint4*)(bp + (size_t)c3 * 128);
            a[0] += (__uint_as_float(u0.x << 16) + __uint_as_float(u1.x << 16)) +
                    (__uint_as_float(u2.x << 16) + __uint_as_float(u3.x << 16));
            a[1] += (__uint_as_float(u0.x & 0xffff0000u) + __uint_as_float(u1.x & 0xffff0000u)) +
                    (__uint_as_float(u2.x & 0xffff0000u) + __uint_as_float(u3.x & 0xffff0000u));
            a[2] += (__uint_as_float(u0.y << 16) + __uint_as_float(u1.y << 16)) +
                    (__uint_as_float(u2.y << 16) + __uint_as_float(u3.y << 16));
            a[3] += (__uint_as_float(u0.y & 0xffff0000u) + __uint_as_float(u1.y & 0xffff0000u)) +
                    (__uint_as_float(u2.y & 0xffff0000u) + __uint_as_float(u3.y & 0xffff0000u));
            a[4] += (__uint_as_float(u0.z << 16) + __uint_as_float(u1.z << 16)) +
                    (__uint_as_float(u2.z << 16) + __uint_as_float(u3.z << 16));
            a[5] += (__uint_as_float(u0.z & 0xffff0000u) + __uint_as_float(u1.z & 0xffff0000u)) +
                    (__uint_as_float(u2.z & 0xffff0000u) + __uint_as_float(u3.z & 0xffff0000u));
            a[6] += (__uint_as_float(u0.w << 16) + __uint_as_float(u1.w << 16)) +
                    (__uint_as_float(u2.w << 16) + __uint_as_float(u3.w << 16));
            a[7] += (__uint_as_float(u0.w & 0xffff0000u) + __uint_as_float(u1.w & 0xffff0000u)) +
                    (__uint_as_float(u2.w & 0xffff0000u) + __uint_as_float(u3.w & 0xffff0000u));
        }
        for (; i + 4 < e; i += 8) {
            const int c0 = colv[i];
            const int c1 = colv[i + 4];
            const uint4 u0 = *(const uint4*)(bp + (size_t)c0 * 128);
            const uint4 u1 = *(const uint4*)(bp + (size_t)c1 * 128);
            a[0] += __uint_as_float(u0.x << 16) + __uint_as_float(u1.x << 16);
            a[1] += __uint_as_float(u0.x & 0xffff0000u) + __uint_as_float(u1.x & 0xffff0000u);
            a[2] += __uint_as_float(u0.y << 16) + __uint_as_float(u1.y << 16);
            a[3] += __uint_as_float(u0.y & 0xffff0000u) + __uint_as_float(u1.y & 0xffff0000u);
            a[4] += __uint_as_float(u0.z << 16) + __uint_as_float(u1.z << 16);
            a[5] += __uint_as_float(u0.z & 0xffff0000u) + __uint_as_float(u1.z & 0xffff0000u);
            a[6] += __uint_as_float(u0.w << 16) + __uint_as_float(u1.w << 16);
            a[7] += __uint_as_float(u0.w & 0xffff0000u) + __uint_as_float(u1.w & 0xffff0000u);
        }
        if (i < e) {
            const int c0 = colv[i];
            const uint4 u0 = *(const uint4*)(bp + (size_t)c0 * 128);
            a[0] += __uint_as_float(u0.x << 16);
            a[1] += __uint_as_float(u0.x & 0xffff0000u);
            a[2] += __uint_as_float(u0.y << 16);
            a[3] += __uint_as_float(u0.y & 0xffff0000u);
            a[4] += __uint_as_float(u0.z << 16);
            a[5] += __uint_as_float(u0.z & 0xffff0000u);
            a[6] += __uint_as_float(u0.w << 16);
            a[7] += __uint_as_float(u0.w & 0xffff0000u);
        }

#pragma unroll
        for (int j = 0; j < 8; j++) {
            a[j] += __shfl_xor(a[j], 16, 64);
            a[j] += __shfl_xor(a[j], 32, 64);
        }

        if (q == 0) {
            const float inv = 1.f / fmaxf((float)(e - s), 1.f);
            ushort16 o[8];
#pragma unroll
            for (int j = 0; j < 8; j++) o[j] = f2bf(fmaxf(a[j] * inv, 0.f));
            *(uint4*)(outp + (size_t)node * 128 + l16 * 8) = *(uint4*)o;
        }
    }
}

// ---------------- post MLP (MFMA 128->128, 128->40) + log_softmax ----------------
__global__ __launch_bounds__(256) void post_mfma(const ushort16* __restrict__ Bb,
                                                 const ushort16* __restrict__ W1b,
                                                 const float* __restrict__ bp1,
                                                 const ushort16* __restrict__ W2b,  // [48][128] padded
                                                 const float* __restrict__ bp2,
                                                 float* __restrict__ Out) {
    __shared__ ushort16 hls[64 * 128];   // h1 bf16, XOR-swizzled
    const int t = threadIdx.x;
    const int w = t >> 6;
    const int l = t & 63;
    const int l15 = l & 15, lh = l >> 4;
    const int rl = w * 16 + l15;               // local row 0..63
    const int rbase = blockIdx.x * 64 + w * 16;
    int arow = rbase + l15;
    if (arow >= NN) arow = NN - 1;

    // ---- stage 1: h1 = X @ Wp1.T + bp1 ----
    {
        f32x4 acc[8];
#pragma unroll
        for (int j = 0; j < 8; j++) acc[j] = (f32x4){0.f, 0.f, 0.f, 0.f};
        const ushort16* ap = Bb + (size_t)arow * 128 + lh * 8;
#pragma unroll
        for (int kk = 0; kk < 4; kk++) {
            const short8 a = *(const short8*)(ap + kk * 32);
#pragma unroll
            for (int j = 0; j < 8; j++) {
                const short8 b = *(const short8*)(W1b + (size_t)(j * 16 + l15) * 128 + kk * 32 + lh * 8);
                acc[j] = __builtin_amdgcn_mfma_f32_16x16x32_bf16(b, a, acc[j], 0, 0, 0);
            }
        }
        char* lp = (char*)hls;
#pragma unroll
        for (int j = 0; j < 8; j++) {
            const float4 bv = *(const float4*)(bp1 + j * 16 + lh * 4);
            ushort16 o[4] = {f2bf(acc[j][0] + bv.x), f2bf(acc[j][1] + bv.y),
                             f2bf(acc[j][2] + bv.z), f2bf(acc[j][3] + bv.w)};
            const int byte = (rl * 256 + j * 32 + lh * 8) ^ ((rl & 7) << 4);
            *(uint2*)(lp + byte) = *(uint2*)o;
        }
    }
    __syncthreads();

    // ---- stage 2: logits = h1 @ Wp2.T + bp2 (48-padded), log_softmax ----
    {
        f32x4 acc[3];
#pragma unroll
        for (int j = 0; j < 3; j++) acc[j] = (f32x4){0.f, 0.f, 0.f, 0.f};
        const char* lp = (const char*)hls;
#pragma unroll
        for (int kk = 0; kk < 4; kk++) {
            const int byte = (rl * 256 + kk * 64 + lh * 16) ^ ((rl & 7) << 4);
            const short8 a = *(const short8*)(lp + byte);
#pragma unroll
            for (int j = 0; j < 3; j++) {
                const short8 b = *(const short8*)(W2b + (size_t)(j * 16 + l15) * 128 + kk * 32 + lh * 8);
                acc[j] = __builtin_amdgcn_mfma_f32_16x16x32_bf16(b, a, acc[j], 0, 0, 0);
            }
        }

        float v[3][4];
        float m = -1e30f;
#pragma unroll
        for (int j = 0; j < 3; j++) {
            const bool val = (j < 2) || (lh < 2);
            if (val) {
                const float4 bv = *(const float4*)(bp2 + j * 16 + lh * 4);
                v[j][0] = acc[j][0] + bv.x;
                v[j][1] = acc[j][1] + bv.y;
                v[j][2] = acc[j][2] + bv.z;
                v[j][3] = acc[j][3] + bv.w;
#pragma unroll
                for (int r = 0; r < 4; r++) m = fmaxf(m, v[j][r]);
            } else {
#pragma unroll
                for (int r = 0; r < 4; r++) v[j][r] = -1e30f;
            }
        }
        m = fmaxf(m, __shfl_xor(m, 16, 64));
        m = fmaxf(m, __shfl_xor(m, 32, 64));
        float se = 0.f;
#pragma unroll
        for (int j = 0; j < 3; j++)
#pragma unroll
            for (int r = 0; r < 4; r++) se += expf(v[j][r] - m);
        se += __shfl_xor(se, 16, 64);
        se += __shfl_xor(se, 32, 64);
        const float lse = logf(se) + m;

        const int row = rbase + l15;
        if (row < NN) {
            float* op = Out + (size_t)row * 40;
#pragma unroll
            for (int j = 0; j < 3; j++) {
                if (j == 2 && lh >= 2) continue;
                float4 o;
                o.x = v[j][0] - lse; o.y = v[j][1] - lse;
                o.z = v[j][2] - lse; o.w = v[j][3] - lse;
                *(float4*)(op + j * 16 + lh * 4) = o;
            }
        }
    }
}

extern "C" void kernel_launch(void* const* d_in, const int* in_sizes, int n_in,
                              void* d_out, int out_size, void* d_ws, size_t ws_size,
                              hipStream_t stream) {
    const float* x   = (const float*)d_in[0];
    const int*   ei  = (const int*)d_in[1];
    const float* W0  = (const float*)d_in[2];
    const float* b0  = (const float*)d_in[3];
    const float* W1  = (const float*)d_in[4];
    const float* b1  = (const float*)d_in[5];
    const float* W2  = (const float*)d_in[6];
    const float* b2  = (const float*)d_in[7];
    const float* Wp1 = (const float*)d_in[8];
    const float* bp1 = (const float*)d_in[9];
    const float* Wp2 = (const float*)d_in[10];
    const float* bp2 = (const float*)d_in[11];
    float* out = (float*)d_out;

    const int E = in_sizes[1] / 2;
    const int* srcv = ei;
    const int* dstv = ei + E;

    char* w = (char*)d_ws;
    auto alloc = [&](size_t sz) {
        char* p = w;
        w += (sz + 255) & ~(size_t)255;
        return p;
    };
    ushort16* Xb  = (ushort16*)alloc(sizeof(ushort16) * (size_t)NN * 128);  // x bf16
    ushort16* H   = (ushort16*)alloc(sizeof(ushort16) * (size_t)NN * 128);  // lin out bf16
    ushort16* Bb  = (ushort16*)alloc(sizeof(ushort16) * (size_t)NN * 128);  // agg out bf16
    uint32* ebuf  = (uint32*)alloc(sizeof(uint32) * (size_t)NB * CAP);
    int*   colv   = (int*)alloc(sizeof(int) * (size_t)E);
    int*   rowptr = (int*)alloc(sizeof(int) * (NN + 1));
    int*   cursor = (int*)alloc(sizeof(int) * NB);
    int*   bstart = (int*)alloc(sizeof(int) * NB);
    ushort16* Wb0 = (ushort16*)alloc(sizeof(ushort16) * 128 * 128);
    ushort16* Wb1 = (ushort16*)alloc(sizeof(ushort16) * 128 * 128);
    ushort16* Wb2 = (ushort16*)alloc(sizeof(ushort16) * 128 * 128);
    ushort16* Wb3 = (ushort16*)alloc(sizeof(ushort16) * 128 * 128);
    ushort16* Wb4 = (ushort16*)alloc(sizeof(ushort16) * 48 * 128);

    // converts
    conv_bf16<<<(NN * 128 / 4 + 255) / 256, 256, 0, stream>>>((const float4*)x, (uint2*)Xb, NN * 128 / 4);
    conv_bf16<<<16, 256, 0, stream>>>((const float4*)W0, (uint2*)Wb0, 4096);
    conv_bf16<<<16, 256, 0, stream>>>((const float4*)W1, (uint2*)Wb1, 4096);
    conv_bf16<<<16, 256, 0, stream>>>((const float4*)W2, (uint2*)Wb2, 4096);
    conv_bf16<<<16, 256, 0, stream>>>((const float4*)Wp1, (uint2*)Wb3, 4096);
    conv_pad_w2<<<6, 256, 0, stream>>>(Wp2, Wb4);

    // CSR build (bucketed counting sort)
    hipMemsetAsync(cursor, 0, sizeof(int) * NB, stream);
    csr_k1<<<(E + CHUNK - 1) / CHUNK, 256, 0, stream>>>(srcv, dstv, E, cursor, ebuf);
    scanb_k<<<1, 512, 0, stream>>>(cursor, bstart);
    csr_k2<<<(NN + NLOC - 1) / NLOC, 256, 0, stream>>>(ebuf, cursor, bstart, rowptr, colv, E);

    const int nlb = (NN + 63) / 64;   // 1563
    // 3 SAGE layers
    lin_mfma<<<nlb, 256, 0, stream>>>(Xb, Wb0, b0, H);
    agg_k<<<4096, 256, 0, stream>>>(H, rowptr, colv, Bb);
    lin_mfma<<<nlb, 256, 0, stream>>>(Bb, Wb1, b1, H);
    agg_k<<<4096, 256, 0, stream>>>(H, rowptr, colv, Bb);
    lin_mfma<<<nlb, 256, 0, stream>>>(Bb, Wb2, b2, H);
    agg_k<<<4096, 256, 0, stream>>>(H, rowptr, colv, Bb);

    // post-MLP + log_softmax
    post_mfma<<<nlb, 256, 0, stream>>>(Bb, Wb3, bp1, Wb4, bp2, out);
}

// Round 6
// 377.230 us; speedup vs baseline: 4.3363x; 1.3797x over previous
//
#include <hip/hip_runtime.h>
#include <cmath>

#define NN 100000
#define NB 512          // dst buckets
#define NLOC 196        // nodes per bucket
#define CAP 7168        // per-bucket edge capacity
#define CHUNK 8192      // edges per csr_k1 block

typedef unsigned int uint32;
typedef unsigned short ushort16;
typedef __attribute__((ext_vector_type(8))) short short8;
typedef __attribute__((ext_vector_type(4))) float f32x4;
typedef __attribute__((ext_vector_type(2))) float f32x2;

#if defined(__has_builtin)
#if __has_builtin(__builtin_amdgcn_cvt_pk_f32_fp8) && __has_builtin(__builtin_amdgcn_cvt_pk_fp8_f32)
#define HAS_HW_FP8 1
#endif
#endif

__device__ __forceinline__ ushort16 f2bf(float f) {
    uint32 b = __float_as_uint(f);
    uint32 r = (b + 0x7FFFu + ((b >> 16) & 1u)) >> 16;   // RNE
    return (ushort16)r;
}

#ifdef HAS_HW_FP8
__device__ __forceinline__ uint32 pack4_e4m3(float a, float b, float c, float d) {
    int v = 0;
    v = __builtin_amdgcn_cvt_pk_fp8_f32(a, b, v, false);
    v = __builtin_amdgcn_cvt_pk_fp8_f32(c, d, v, true);
    return (uint32)v;
}
#else
__device__ __forceinline__ uint32 enc1_e4m3(float f) {
    uint32 bits = __float_as_uint(f);
    uint32 s = (bits >> 24) & 0x80u;
    float a = fabsf(f);
    if (a >= 448.f) return s | 0x7Eu;
    if (a < 0.0009765625f) return s;
    if (a < 0.015625f) return s | (uint32)rintf(a * 512.f);
    int e; float m = frexpf(a, &e);
    uint32 q = (uint32)rintf(m * 16.f);
    if (q == 16) { q = 8; e++; }
    return s | ((uint32)(e + 6) << 3) | (q - 8);
}
__device__ __forceinline__ uint32 pack4_e4m3(float a, float b, float c, float d) {
    return enc1_e4m3(a) | (enc1_e4m3(b) << 8) | (enc1_e4m3(c) << 16) | (enc1_e4m3(d) << 24);
}
#endif

#ifdef HAS_HW_FP8
#define DEC_PK(u, w) __builtin_amdgcn_cvt_pk_f32_fp8((int)(u), (w))
#else
__device__ __forceinline__ float dec1_e4m3(uint32 u) {
    uint32 s = (u & 0x80u) << 24;
    uint32 em = u & 0x7Fu;
    if (em >= 8)
        return __uint_as_float(s | (((em >> 3) + 120u) << 23) | ((em & 7u) << 20));
    return __uint_as_float(s | 0x3F800000u) * 0.f + ((u & 0x80u) ? -1.f : 1.f) * (float)em * 0.001953125f;
}
__device__ __forceinline__ f32x2 DEC_PK(uint32 u, bool w) {
    uint32 h = w ? (u >> 16) : u;
    f32x2 r; r.x = dec1_e4m3(h & 0xFF); r.y = dec1_e4m3((h >> 8) & 0xFF);
    return r;
}
#endif

// ---------------- f32 -> bf16 convert (weights only, tiny) ----------------
__global__ void conv_bf16(const float4* __restrict__ in, uint2* __restrict__ out, int n4) {
    int i = blockIdx.x * 256 + threadIdx.x;
    if (i >= n4) return;
    const float4 v = in[i];
    ushort16 o[4] = {f2bf(v.x), f2bf(v.y), f2bf(v.z), f2bf(v.w)};
    out[i] = *(uint2*)o;
}

// Wp2 [40][128] f32 -> [48][128] bf16 zero-padded rows
__global__ void conv_pad_w2(const float* __restrict__ in, ushort16* __restrict__ out) {
    int i = blockIdx.x * 256 + threadIdx.x;     // 1536 quads
    if (i >= 48 * 128 / 4) return;
    int e = i * 4;
    int j = e >> 7, k = e & 127;
    ushort16 o[4];
#pragma unroll
    for (int c = 0; c < 4; c++) o[c] = (j < 40) ? f2bf(in[j * 128 + k + c]) : (ushort16)0;
    *(uint2*)(out + e) = *(uint2*)o;
}

// ---------------- CSR build: pass 1 — bucket partition ----------------
__global__ __launch_bounds__(256) void csr_k1(const int* __restrict__ srcv,
                                              const int* __restrict__ dstv, int E,
                                              int* __restrict__ cursor,
                                              uint32* __restrict__ ebuf) {
    __shared__ int lhist[NB];
    __shared__ int lbase[NB];
    __shared__ int lcnt[NB];
    const int t = threadIdx.x;
    const int e0 = blockIdx.x * CHUNK;
    const int e1 = min(e0 + CHUNK, E);

    for (int i = t; i < NB; i += 256) { lhist[i] = 0; lcnt[i] = 0; }
    __syncthreads();
    for (int i = e0 + t; i < e1; i += 256)
        atomicAdd(&lhist[dstv[i] / NLOC], 1);
    __syncthreads();
    for (int i = t; i < NB; i += 256)
        lbase[i] = lhist[i] ? atomicAdd(&cursor[i], lhist[i]) : 0;
    __syncthreads();
    for (int i = e0 + t; i < e1; i += 256) {
        const int d = dstv[i];
        const int s = srcv[i];
        const int b = d / NLOC;
        const int pos = lbase[b] + atomicAdd(&lcnt[b], 1);
        if (pos < CAP)
            ebuf[(size_t)b * CAP + pos] = (uint32)s | ((uint32)(d - b * NLOC) << 17);
    }
}

__global__ __launch_bounds__(512) void scanb_k(const int* __restrict__ cursor,
                                               int* __restrict__ bstart) {
    __shared__ int sd[512];
    const int t = threadIdx.x;
    const int v = cursor[t];
    sd[t] = v;
    __syncthreads();
    for (int off = 1; off < 512; off <<= 1) {
        int x = (t >= off) ? sd[t - off] : 0;
        __syncthreads();
        sd[t] += x;
        __syncthreads();
    }
    bstart[t] = sd[t] - v;   // exclusive
}

__global__ __launch_bounds__(256) void csr_k2(const uint32* __restrict__ ebuf,
                                              const int* __restrict__ cursor,
                                              const int* __restrict__ bstart,
                                              int* __restrict__ rowptr,
                                              int* __restrict__ colv, int Etot) {
    __shared__ int sd[256];
    __shared__ int loc[256];
    __shared__ int cnt[256];
    const int b = blockIdx.x;
    const int t = threadIdx.x;
    const int n = cursor[b];
    const int n0 = b * NLOC;
    const int nloc = min(NN - n0, NLOC);
    const int bst = bstart[b];
    const uint32* seg = ebuf + (size_t)b * CAP;

    sd[t] = 0; cnt[t] = 0;
    __syncthreads();
    for (int i = t; i < n; i += 256)
        atomicAdd(&sd[seg[i] >> 17], 1);
    __syncthreads();
    const int v = sd[t];
    __syncthreads();
    for (int off = 1; off < 256; off <<= 1) {
        int x = (t >= off) ? sd[t - off] : 0;
        __syncthreads();
        sd[t] += x;
        __syncthreads();
    }
    loc[t] = sd[t] - v;
    __syncthreads();
    if (t < nloc) rowptr[n0 + t] = bst + loc[t];
    if (b == 0 && t == 0) rowptr[NN] = Etot;
    for (int i = t; i < n; i += 256) {
        const uint32 p = seg[i];
        const int l = p >> 17;
        const int src = p & 0x1FFFF;
        const int pos = atomicAdd(&cnt[l], 1);
        colv[bst + loc[l] + pos] = src;
    }
}

// ---------------- MFMA projection + L2 normalize -> fp8 h table ----------------
// F32IN=1: A operand from f32 global (layer 0); else bf16 table.
template <int F32IN>
__global__ __launch_bounds__(256) void lin_mfma(const void* __restrict__ Xin,
                                                const ushort16* __restrict__ Wb,
                                                const float* __restrict__ bias,
                                                unsigned char* __restrict__ Y8) {
    __shared__ short8 wls[2048];      // [j][kk][lane] 16B fragments = 32 KB
    const int t = threadIdx.x;
    const int l = t & 63;
    const int l15 = l & 15, lh = l >> 4;
    const int rbase = blockIdx.x * 64 + (t >> 6) * 16;
    int arow = rbase + l15;
    if (arow >= NN) arow = NN - 1;

    // stage W fragments
#pragma unroll
    for (int it = 0; it < 8; it++) {
        const int idx = it * 256 + t;
        const int j = idx >> 8, kk = (idx >> 6) & 3, ll = idx & 63;
        wls[idx] = *(const short8*)((const ushort16*)Wb + (size_t)(j * 16 + (ll & 15)) * 128 + kk * 32 + (ll >> 4) * 8);
    }

    // hoist A fragments
    short8 a[4];
    if (F32IN) {
        const float* ap = (const float*)Xin + (size_t)arow * 128 + lh * 8;
#pragma unroll
        for (int kk = 0; kk < 4; kk++) {
            const float4 p0 = *(const float4*)(ap + kk * 32);
            const float4 p1 = *(const float4*)(ap + kk * 32 + 4);
            ushort16 o[8] = {f2bf(p0.x), f2bf(p0.y), f2bf(p0.z), f2bf(p0.w),
                             f2bf(p1.x), f2bf(p1.y), f2bf(p1.z), f2bf(p1.w)};
            a[kk] = *(short8*)o;
        }
    } else {
        const ushort16* ap = (const ushort16*)Xin + (size_t)arow * 128 + lh * 8;
#pragma unroll
        for (int kk = 0; kk < 4; kk++) a[kk] = *(const short8*)(ap + kk * 32);
    }

    __syncthreads();

    f32x4 acc[8];
#pragma unroll
    for (int j = 0; j < 8; j++) acc[j] = (f32x4){0.f, 0.f, 0.f, 0.f};

#pragma unroll
    for (int kk = 0; kk < 4; kk++)
#pragma unroll
        for (int j = 0; j < 8; j++)
            acc[j] = __builtin_amdgcn_mfma_f32_16x16x32_bf16(wls[j * 256 + kk * 64 + l], a[kk], acc[j], 0, 0, 0);

    float v[8][4];
    float ssq = 0.f;
#pragma unroll
    for (int j = 0; j < 8; j++) {
        const float4 bv = *(const float4*)(bias + j * 16 + lh * 4);
        v[j][0] = acc[j][0] + bv.x;
        v[j][1] = acc[j][1] + bv.y;
        v[j][2] = acc[j][2] + bv.z;
        v[j][3] = acc[j][3] + bv.w;
        ssq += v[j][0] * v[j][0] + v[j][1] * v[j][1] + v[j][2] * v[j][2] + v[j][3] * v[j][3];
    }
    ssq += __shfl_xor(ssq, 16, 64);
    ssq += __shfl_xor(ssq, 32, 64);
    const float sc = 1.f / fmaxf(sqrtf(ssq), 1e-12f);

    const int row = rbase + l15;
    if (row < NN) {
        unsigned char* yp = Y8 + (size_t)row * 128;
#pragma unroll
        for (int j = 0; j < 8; j++) {
            const uint32 p = pack4_e4m3(v[j][0] * sc, v[j][1] * sc, v[j][2] * sc, v[j][3] * sc);
            *(uint32*)(yp + j * 16 + lh * 4) = p;
        }
    }
}

// ---------------- CSR mean-aggregate + ReLU (fp8 gather -> bf16 out) ----------------
// quarter-wave = 16 lanes x 8B = one 128B fp8 row; 4 rows deep per quarter.
__global__ __launch_bounds__(256) void agg_k(const unsigned char* __restrict__ hp,
                                             const int* __restrict__ rowptr,
                                             const int* __restrict__ colv,
                                             ushort16* __restrict__ outp) {
    const int lane = threadIdx.x & 63;
    const int q = lane >> 4;
    const int l16 = lane & 15;
    const int wid = blockIdx.x * 4 + (threadIdx.x >> 6);
    const int nw = gridDim.x * 4;

    for (int node = wid; node < NN; node += nw) {
        const int s = rowptr[node], e = rowptr[node + 1];
        float a[8] = {};
        const unsigned char* bp = hp + (size_t)l16 * 8;

        int i = s + q;
        for (; i + 12 < e; i += 16) {
            const int c0 = colv[i];
            const int c1 = colv[i + 4];
            const int c2 = colv[i + 8];
            const int c3 = colv[i + 12];
            const uint2 u0 = *(const uint2*)(bp + (size_t)c0 * 128);
            const uint2 u1 = *(const uint2*)(bp + (size_t)c1 * 128);
            const uint2 u2 = *(const uint2*)(bp + (size_t)c2 * 128);
            const uint2 u3 = *(const uint2*)(bp + (size_t)c3 * 128);
#pragma unroll
            for (int r = 0; r < 4; r++) {
                const uint2 u = (r == 0) ? u0 : (r == 1) ? u1 : (r == 2) ? u2 : u3;
                const f32x2 p0 = DEC_PK(u.x, false);
                const f32x2 p1 = DEC_PK(u.x, true);
                const f32x2 p2 = DEC_PK(u.y, false);
                const f32x2 p3 = DEC_PK(u.y, true);
                a[0] += p0.x; a[1] += p0.y; a[2] += p1.x; a[3] += p1.y;
                a[4] += p2.x; a[5] += p2.y; a[6] += p3.x; a[7] += p3.y;
            }
        }
        for (; i < e; i += 4) {
            const int c0 = colv[i];
            const uint2 u = *(const uint2*)(bp + (size_t)c0 * 128);
            const f32x2 p0 = DEC_PK(u.x, false);
            const f32x2 p1 = DEC_PK(u.x, true);
            const f32x2 p2 = DEC_PK(u.y, false);
            const f32x2 p3 = DEC_PK(u.y, true);
            a[0] += p0.x; a[1] += p0.y; a[2] += p1.x; a[3] += p1.y;
            a[4] += p2.x; a[5] += p2.y; a[6] += p3.x; a[7] += p3.y;
        }

#pragma unroll
        for (int j = 0; j < 8; j++) {
            a[j] += __shfl_xor(a[j], 16, 64);
            a[j] += __shfl_xor(a[j], 32, 64);
        }

        if (q == 0) {
            const float inv = 1.f / fmaxf((float)(e - s), 1.f);
            ushort16 o[8];
#pragma unroll
            for (int j = 0; j < 8; j++) o[j] = f2bf(fmaxf(a[j] * inv, 0.f));
            *(uint4*)(outp + (size_t)node * 128 + l16 * 8) = *(uint4*)o;
        }
    }
}

// ---------------- post MLP (MFMA 128->128, 128->40) + log_softmax ----------------
__global__ __launch_bounds__(256) void post_mfma(const ushort16* __restrict__ Bb,
                                                 const ushort16* __restrict__ W1b,
                                                 const float* __restrict__ bp1,
                                                 const ushort16* __restrict__ W2b,  // [48][128] padded
                                                 const float* __restrict__ bp2,
                                                 float* __restrict__ Out) {
    __shared__ ushort16 hls[64 * 128];   // h1 bf16, XOR-swizzled
    const int t = threadIdx.x;
    const int w = t >> 6;
    const int l = t & 63;
    const int l15 = l & 15, lh = l >> 4;
    const int rl = w * 16 + l15;               // local row 0..63
    const int rbase = blockIdx.x * 64 + w * 16;
    int arow = rbase + l15;
    if (arow >= NN) arow = NN - 1;

    // ---- stage 1: h1 = X @ Wp1.T + bp1 ----
    {
        f32x4 acc[8];
#pragma unroll
        for (int j = 0; j < 8; j++) acc[j] = (f32x4){0.f, 0.f, 0.f, 0.f};
        const ushort16* ap = Bb + (size_t)arow * 128 + lh * 8;
#pragma unroll
        for (int kk = 0; kk < 4; kk++) {
            const short8 a = *(const short8*)(ap + kk * 32);
#pragma unroll
            for (int j = 0; j < 8; j++) {
                const short8 b = *(const short8*)(W1b + (size_t)(j * 16 + l15) * 128 + kk * 32 + lh * 8);
                acc[j] = __builtin_amdgcn_mfma_f32_16x16x32_bf16(b, a, acc[j], 0, 0, 0);
            }
        }
        char* lp = (char*)hls;
#pragma unroll
        for (int j = 0; j < 8; j++) {
            const float4 bv = *(const float4*)(bp1 + j * 16 + lh * 4);
            ushort16 o[4] = {f2bf(acc[j][0] + bv.x), f2bf(acc[j][1] + bv.y),
                             f2bf(acc[j][2] + bv.z), f2bf(acc[j][3] + bv.w)};
            const int byte = (rl * 256 + j * 32 + lh * 8) ^ ((rl & 7) << 4);
            *(uint2*)(lp + byte) = *(uint2*)o;
        }
    }
    __syncthreads();

    // ---- stage 2: logits = h1 @ Wp2.T + bp2 (48-padded), log_softmax ----
    {
        f32x4 acc[3];
#pragma unroll
        for (int j = 0; j < 3; j++) acc[j] = (f32x4){0.f, 0.f, 0.f, 0.f};
        const char* lp = (const char*)hls;
#pragma unroll
        for (int kk = 0; kk < 4; kk++) {
            const int byte = (rl * 256 + kk * 64 + lh * 16) ^ ((rl & 7) << 4);
            const short8 a = *(const short8*)(lp + byte);
#pragma unroll
            for (int j = 0; j < 3; j++) {
                const short8 b = *(const short8*)(W2b + (size_t)(j * 16 + l15) * 128 + kk * 32 + lh * 8);
                acc[j] = __builtin_amdgcn_mfma_f32_16x16x32_bf16(b, a, acc[j], 0, 0, 0);
            }
        }

        float v[3][4];
        float m = -1e30f;
#pragma unroll
        for (int j = 0; j < 3; j++) {
            const bool val = (j < 2) || (lh < 2);
            if (val) {
                const float4 bv = *(const float4*)(bp2 + j * 16 + lh * 4);
                v[j][0] = acc[j][0] + bv.x;
                v[j][1] = acc[j][1] + bv.y;
                v[j][2] = acc[j][2] + bv.z;
                v[j][3] = acc[j][3] + bv.w;
#pragma unroll
                for (int r = 0; r < 4; r++) m = fmaxf(m, v[j][r]);
            } else {
#pragma unroll
                for (int r = 0; r < 4; r++) v[j][r] = -1e30f;
            }
        }
        m = fmaxf(m, __shfl_xor(m, 16, 64));
        m = fmaxf(m, __shfl_xor(m, 32, 64));
        float se = 0.f;
#pragma unroll
        for (int j = 0; j < 3; j++)
#pragma unroll
            for (int r = 0; r < 4; r++) se += expf(v[j][r] - m);
        se += __shfl_xor(se, 16, 64);
        se += __shfl_xor(se, 32, 64);
        const float lse = logf(se) + m;

        const int row = rbase + l15;
        if (row < NN) {
            float* op = Out + (size_t)row * 40;
#pragma unroll
            for (int j = 0; j < 3; j++) {
                if (j == 2 && lh >= 2) continue;
                float4 o;
                o.x = v[j][0] - lse; o.y = v[j][1] - lse;
                o.z = v[j][2] - lse; o.w = v[j][3] - lse;
                *(float4*)(op + j * 16 + lh * 4) = o;
            }
        }
    }
}

extern "C" void kernel_launch(void* const* d_in, const int* in_sizes, int n_in,
                              void* d_out, int out_size, void* d_ws, size_t ws_size,
                              hipStream_t stream) {
    const float* x   = (const float*)d_in[0];
    const int*   ei  = (const int*)d_in[1];
    const float* W0  = (const float*)d_in[2];
    const float* b0  = (const float*)d_in[3];
    const float* W1  = (const float*)d_in[4];
    const float* b1  = (const float*)d_in[5];
    const float* W2  = (const float*)d_in[6];
    const float* b2  = (const float*)d_in[7];
    const float* Wp1 = (const float*)d_in[8];
    const float* bp1 = (const float*)d_in[9];
    const float* Wp2 = (const float*)d_in[10];
    const float* bp2 = (const float*)d_in[11];
    float* out = (float*)d_out;

    const int E = in_sizes[1] / 2;
    const int* srcv = ei;
    const int* dstv = ei + E;

    char* w = (char*)d_ws;
    auto alloc = [&](size_t sz) {
        char* p = w;
        w += (sz + 255) & ~(size_t)255;
        return p;
    };
    unsigned char* H8 = (unsigned char*)alloc((size_t)NN * 128);            // fp8 h table
    ushort16* Bb  = (ushort16*)alloc(sizeof(ushort16) * (size_t)NN * 128);  // agg out bf16
    uint32* ebuf  = (uint32*)alloc(sizeof(uint32) * (size_t)NB * CAP);
    int*   colv   = (int*)alloc(sizeof(int) * (size_t)E);
    int*   rowptr = (int*)alloc(sizeof(int) * (NN + 1));
    int*   cursor = (int*)alloc(sizeof(int) * NB);
    int*   bstart = (int*)alloc(sizeof(int) * NB);
    ushort16* Wb0 = (ushort16*)alloc(sizeof(ushort16) * 128 * 128);
    ushort16* Wb1 = (ushort16*)alloc(sizeof(ushort16) * 128 * 128);
    ushort16* Wb2 = (ushort16*)alloc(sizeof(ushort16) * 128 * 128);
    ushort16* Wb3 = (ushort16*)alloc(sizeof(ushort16) * 128 * 128);
    ushort16* Wb4 = (ushort16*)alloc(sizeof(ushort16) * 48 * 128);

    // weight converts (tiny)
    conv_bf16<<<16, 256, 0, stream>>>((const float4*)W0, (uint2*)Wb0, 4096);
    conv_bf16<<<16, 256, 0, stream>>>((const float4*)W1, (uint2*)Wb1, 4096);
    conv_bf16<<<16, 256, 0, stream>>>((const float4*)W2, (uint2*)Wb2, 4096);
    conv_bf16<<<16, 256, 0, stream>>>((const float4*)Wp1, (uint2*)Wb3, 4096);
    conv_pad_w2<<<6, 256, 0, stream>>>(Wp2, Wb4);

    // CSR build (bucketed counting sort)
    hipMemsetAsync(cursor, 0, sizeof(int) * NB, stream);
    csr_k1<<<(E + CHUNK - 1) / CHUNK, 256, 0, stream>>>(srcv, dstv, E, cursor, ebuf);
    scanb_k<<<1, 512, 0, stream>>>(cursor, bstart);
    csr_k2<<<(NN + NLOC - 1) / NLOC, 256, 0, stream>>>(ebuf, cursor, bstart, rowptr, colv, E);

    const int nlb = (NN + 63) / 64;   // 1563
    // 3 SAGE layers (layer 0 reads f32 x directly)
    lin_mfma<1><<<nlb, 256, 0, stream>>>(x, Wb0, b0, H8);
    agg_k<<<4096, 256, 0, stream>>>(H8, rowptr, colv, Bb);
    lin_mfma<0><<<nlb, 256, 0, stream>>>(Bb, Wb1, b1, H8);
    agg_k<<<4096, 256, 0, stream>>>(H8, rowptr, colv, Bb);
    lin_mfma<0><<<nlb, 256, 0, stream>>>(Bb, Wb2, b2, H8);
    agg_k<<<4096, 256, 0, stream>>>(H8, rowptr, colv, Bb);

    // post-MLP + log_softmax
    post_mfma<<<nlb, 256, 0, stream>>>(Bb, Wb3, bp1, Wb4, bp2, out);
}